// Round 1
// baseline (1696.492 us; speedup 1.0000x reference)
//
#include <hip/hip_runtime.h>
#include <hip/hip_bf16.h>
#include <math.h>

#define HEADS 16
#define DIM 1024
#define HD 64
#define N_TEXT 16
#define F_TOK 1568
#define NTOK 1584
#define MPAD 1664
#define SCALEF 0.125f

typedef unsigned int uint;
typedef unsigned short u16;

typedef __bf16 bf16x8 __attribute__((ext_vector_type(8)));
typedef float f32x4 __attribute__((ext_vector_type(4)));

__device__ inline u16 f2b(float f){
  uint u = __builtin_bit_cast(uint, f);
  uint r = u + 0x7fffu + ((u >> 16) & 1u);
  return (u16)(r >> 16);
}

__device__ inline f32x4 mfma16(bf16x8 a, bf16x8 b, f32x4 c){
  return __builtin_amdgcn_mfma_f32_16x16x32_bf16(a, b, c, 0, 0, 0);
}

// ---------------- weight transpose fp32[K][N] -> bf16[N][K] ----------------
__global__ __launch_bounds__(256) void wtrans_kernel(const float* __restrict__ src,
                                                     u16* __restrict__ dst, int K, int N){
  __shared__ float tile[32][33];
  int n0 = blockIdx.x * 32, k0 = blockIdx.y * 32;
  int t = threadIdx.x;
  int col = t & 31, rb = t >> 5;
#pragma unroll
  for (int p = 0; p < 4; ++p){
    int row = p*8 + rb;
    tile[row][col] = src[(size_t)(k0+row)*N + n0 + col];
  }
  __syncthreads();
#pragma unroll
  for (int p = 0; p < 4; ++p){
    int rn = p*8 + rb;
    dst[(size_t)(n0+rn)*K + k0 + col] = f2b(tile[col][rn]);
  }
}

// ---------------- flat fp32 -> bf16 ----------------
__global__ __launch_bounds__(256) void f2b_kernel(const float* __restrict__ src,
                                                  u16* __restrict__ dst, int n){
  int i = blockIdx.x*256 + threadIdx.x;
  if (i < n) dst[i] = f2b(src[i]);
}

// ---------------- rope tables ----------------
__global__ __launch_bounds__(256) void rope_table_kernel(float* __restrict__ ct,
                                                         float* __restrict__ st){
  int i = blockIdx.x*256 + threadIdx.x;
  if (i >= NTOK*64) return;
  int n = i >> 6, d = i & 63;
  float f = 0.f;
  if (n >= N_TEXT){
    int id = n - N_TEXT;
    int p0 = id / 196;
    int p1 = (id % 196) / 14;
    int p2 = id % 14;
    float pos = 0.f; int j = -1;
    if (d < 20){ pos = (float)p0; j = d >> 1; }
    else if (d < 40){ pos = (float)p1; j = (d-20) >> 1; }
    else if (d < 60){ pos = (float)p2; j = (d-40) >> 1; }
    if (j >= 0){
      float inv = powf(10000.f, -(float)j * 0.1f);
      f = pos * inv;
    }
  }
  ct[i] = cosf(f);
  st[i] = sinf(f);
}

// ---------------- rope apply + split qkv -> per-head bf16 ----------------
__global__ __launch_bounds__(256) void rope_apply_kernel(const float* __restrict__ qkv,
    const float* __restrict__ ct, const float* __restrict__ st,
    u16* __restrict__ qb, u16* __restrict__ kb, u16* __restrict__ vb){
  int i = blockIdx.x*256 + threadIdx.x;       // NTOK*16*32
  if (i >= NTOK*HEADS*32) return;
  int n = i / 512;
  int rem = i & 511;
  int h = rem >> 5;
  int d0 = (rem & 31) * 2;
  size_t base = (size_t)n*3072 + h*64 + d0;
  float q0 = qkv[base],      q1 = qkv[base+1];
  float k0 = qkv[base+1024], k1 = qkv[base+1025];
  float v0 = qkv[base+2048], v1 = qkv[base+2049];
  float c = ct[n*64+d0], s = st[n*64+d0];     // cos[2i]==cos[2i+1]
  size_t ob = ((size_t)h*MPAD + n)*64 + d0;
  qb[ob]   = f2b(q0*c - q1*s);
  qb[ob+1] = f2b(q1*c + q0*s);
  kb[ob]   = f2b(k0*c - k1*s);
  kb[ob+1] = f2b(k1*c + k0*s);
  vb[ob]   = f2b(v0);
  vb[ob+1] = f2b(v1);
}

// ---------------- layernorm (fp32 in, bf16 out) ----------------
__global__ __launch_bounds__(256) void ln_kernel(const float* __restrict__ x,
    const float* __restrict__ w, const float* __restrict__ b, u16* __restrict__ out){
  int row = blockIdx.x, t = threadIdx.x;
  const float* xr = x + (size_t)row * DIM;
  float4 v = *(const float4*)&xr[t*4];
  float s = v.x+v.y+v.z+v.w;
  float ss = v.x*v.x+v.y*v.y+v.z*v.z+v.w*v.w;
#pragma unroll
  for (int o=32;o>0;o>>=1){ s += __shfl_down(s,o,64); ss += __shfl_down(ss,o,64); }
  __shared__ float red[8];
  int wid = t>>6;
  if ((t&63)==0){ red[wid] = s; red[4+wid] = ss; }
  __syncthreads();
  float S = red[0]+red[1]+red[2]+red[3];
  float SS = red[4]+red[5]+red[6]+red[7];
  float mean = S * (1.0f/1024.0f);
  float var = SS * (1.0f/1024.0f) - mean*mean;
  float inv = rsqrtf(var + 1e-5f);
  ushort4 o4;
  o4.x = f2b((v.x-mean)*inv*w[t*4+0]+b[t*4+0]);
  o4.y = f2b((v.y-mean)*inv*w[t*4+1]+b[t*4+1]);
  o4.z = f2b((v.z-mean)*inv*w[t*4+2]+b[t*4+2]);
  o4.w = f2b((v.w-mean)*inv*w[t*4+3]+b[t*4+3]);
  *(ushort4*)&out[(size_t)row*DIM + t*4] = o4;
}

// ---------------- generic bf16 MFMA GEMM: C = A[M][K] @ BT[N][K]^T + bias ----------------
// EPI: 0 = bias -> fp32 ; 2 = bias + resid -> fp32 ; 3 = bias + gelu -> bf16
template<int EPI>
__global__ __launch_bounds__(256)
void gemm_kernel(const u16* __restrict__ A, const u16* __restrict__ BT,
                 const float* __restrict__ bias, const float* __restrict__ resid,
                 float* __restrict__ outF, u16* __restrict__ outB,
                 int M, int N, int K)
{
  __shared__ u16 Al[128][40];
  __shared__ u16 Bl[128][40];
  int m0 = blockIdx.y * 128, n0 = blockIdx.x * 128;
  int t = threadIdx.x;
  int wid = t >> 6, lane = t & 63;
  int wr = wid >> 1, wc = wid & 1;
  int lr = lane & 15, lg = lane >> 4;

  f32x4 acc[4][4] = {};
  for (int k0 = 0; k0 < K; k0 += 32){
#pragma unroll
    for (int p = 0; p < 2; ++p){
      int sidx = t + p*256;                 // 512 segments: 128 rows x 4 x (8 bf16)
      int row = sidx >> 2, c8 = (sidx & 3) * 8;
      *(uint4*)&Al[row][c8] = *(const uint4*)&A [(size_t)(m0+row)*K + k0 + c8];
      *(uint4*)&Bl[row][c8] = *(const uint4*)&BT[(size_t)(n0+row)*K + k0 + c8];
    }
    __syncthreads();
    bf16x8 af[4], bfv[4];
#pragma unroll
    for (int m=0;m<4;++m) af[m]  = *(const bf16x8*)&Al[wr*64 + m*16 + lr][lg*8];
#pragma unroll
    for (int n=0;n<4;++n) bfv[n] = *(const bf16x8*)&Bl[wc*64 + n*16 + lr][lg*8];
#pragma unroll
    for (int m=0;m<4;++m)
#pragma unroll
      for (int n=0;n<4;++n)
        acc[m][n] = mfma16(af[m], bfv[n], acc[m][n]);
    __syncthreads();
  }
#pragma unroll
  for (int m=0;m<4;++m){
    int rbase = m0 + wr*64 + m*16 + lg*4;
#pragma unroll
    for (int r=0;r<4;++r){
      int row = rbase + r;
      if (row >= M) continue;
#pragma unroll
      for (int n=0;n<4;++n){
        int col = n0 + wc*64 + n*16 + lr;
        float v = acc[m][n][r] + bias[col];
        if constexpr (EPI==2) v += resid[(size_t)row*N + col];
        if constexpr (EPI==3){
          v = 0.5f * v * (1.0f + erff(v * 0.70710678118654752f));
          outB[(size_t)row*N + col] = f2b(v);
        } else {
          outF[(size_t)row*N + col] = v;
        }
      }
    }
  }
}

// ---------------- attention mask bias ----------------
__device__ inline float bias_fn(int qi, int ki){
  if (ki >= NTOK) return -1e9f;
  if (qi < N_TEXT) return (ki <= qi) ? 0.f : -1e9f;
  if (ki < N_TEXT) return 0.f;
  int fq = (qi - N_TEXT) / 196;
  int fk = (ki - N_TEXT) / 196;
  return (fk <= fq) ? 0.f : -1e9f;
}

// ---------------- fused flash attention: per (q-block 128, head) ----------------
__global__ __launch_bounds__(256)
void attn_kernel(const u16* __restrict__ qb, const u16* __restrict__ kb,
                 const u16* __restrict__ vb, u16* __restrict__ ob)
{
  __shared__ u16 Kl[64][72];
  __shared__ u16 Vl[64][72];    // V^T: [d][kk]
  __shared__ u16 Pl[128][72];
  const int hh = blockIdx.y;
  const int q0 = blockIdx.x * 128;
  const int t = threadIdx.x, wid = t>>6, lane = t&63, lr = lane&15, lg = lane>>4;

  bf16x8 qf[2][2];
#pragma unroll
  for (int m=0;m<2;++m)
#pragma unroll
    for (int ks=0;ks<2;++ks){
      int row = q0 + wid*32 + m*16 + lr;
      qf[m][ks] = *(const bf16x8*)&qb[((size_t)hh*MPAD + row)*64 + ks*32 + lg*8];
    }

  float mrun[8], lrun[8];
#pragma unroll
  for (int i=0;i<8;++i){ mrun[i] = -3.0e38f; lrun[i] = 0.0f; }
  f32x4 oacc[2][4] = {};

  for (int kbi = 0; kbi < 25; ++kbi){       // 25*64 = 1600 >= 1584 keys
    int k0 = kbi*64;
#pragma unroll
    for (int p=0;p<2;++p){                  // stage K: 64 rows x 64 d
      int sidx = t + p*256;
      int row = sidx >> 3, c8 = (sidx & 7) * 8;
      *(uint4*)&Kl[row][c8] = *(const uint4*)&kb[((size_t)hh*MPAD + k0 + row)*64 + c8];
    }
#pragma unroll
    for (int p=0;p<2;++p){                  // stage V^T
      int sidx = t + p*256;
      int kk = sidx & 63, d8 = (sidx >> 6) * 8;
      union { uint4 u; u16 s[8]; } tv;
      tv.u = *(const uint4*)&vb[((size_t)hh*MPAD + k0 + kk)*64 + d8];
#pragma unroll
      for (int j=0;j<8;++j) Vl[d8+j][kk] = tv.s[j];
    }
    __syncthreads();

    // QK^T
    f32x4 sacc[2][4] = {};
#pragma unroll
    for (int n=0;n<4;++n){
      bf16x8 kf0 = *(const bf16x8*)&Kl[n*16 + lr][lg*8];
      bf16x8 kf1 = *(const bf16x8*)&Kl[n*16 + lr][32 + lg*8];
#pragma unroll
      for (int m=0;m<2;++m){
        sacc[m][n] = mfma16(qf[m][0], kf0, sacc[m][n]);
        sacc[m][n] = mfma16(qf[m][1], kf1, sacc[m][n]);
      }
    }

    // scale + bias, per-row block max
    float sval[2][4][4];
    float pmax[8];
#pragma unroll
    for (int i=0;i<8;++i) pmax[i] = -3.0e38f;
#pragma unroll
    for (int m=0;m<2;++m)
#pragma unroll
      for (int n=0;n<4;++n)
#pragma unroll
        for (int r=0;r<4;++r){
          int qi = q0 + wid*32 + m*16 + lg*4 + r;
          int ki = k0 + n*16 + lr;
          float v = sacc[m][n][r]*SCALEF + bias_fn(qi, ki);
          sval[m][n][r] = v;
          pmax[m*4+r] = fmaxf(pmax[m*4+r], v);
        }
#pragma unroll
    for (int i=0;i<8;++i){
      float v = pmax[i];
      v = fmaxf(v, __shfl_xor(v,1,64));
      v = fmaxf(v, __shfl_xor(v,2,64));
      v = fmaxf(v, __shfl_xor(v,4,64));
      v = fmaxf(v, __shfl_xor(v,8,64));
      pmax[i] = v;
    }
    float alpha[8], psum[8];
#pragma unroll
    for (int i=0;i<8;++i){
      float mnew = fmaxf(mrun[i], pmax[i]);
      alpha[i] = expf(mrun[i] - mnew);
      mrun[i] = mnew;
      psum[i] = 0.f;
    }
#pragma unroll
    for (int m=0;m<2;++m)
#pragma unroll
      for (int r=0;r<4;++r){
        float mn = mrun[m*4+r];
#pragma unroll
        for (int n=0;n<4;++n){
          float p = expf(sval[m][n][r] - mn);
          psum[m*4+r] += p;
          Pl[wid*32 + m*16 + lg*4 + r][n*16 + lr] = f2b(p);
        }
      }
#pragma unroll
    for (int i=0;i<8;++i){
      float v = psum[i];
      v += __shfl_xor(v,1,64); v += __shfl_xor(v,2,64);
      v += __shfl_xor(v,4,64); v += __shfl_xor(v,8,64);
      lrun[i] = lrun[i]*alpha[i] + v;
    }
#pragma unroll
    for (int m=0;m<2;++m)
#pragma unroll
      for (int n=0;n<4;++n)
#pragma unroll
        for (int r=0;r<4;++r)
          oacc[m][n][r] *= alpha[m*4+r];
    __syncthreads();

    // P @ V
#pragma unroll
    for (int m=0;m<2;++m){
      bf16x8 pf0 = *(const bf16x8*)&Pl[wid*32 + m*16 + lr][lg*8];
      bf16x8 pf1 = *(const bf16x8*)&Pl[wid*32 + m*16 + lr][32 + lg*8];
#pragma unroll
      for (int n=0;n<4;++n){
        bf16x8 vf0 = *(const bf16x8*)&Vl[n*16 + lr][lg*8];
        bf16x8 vf1 = *(const bf16x8*)&Vl[n*16 + lr][32 + lg*8];
        oacc[m][n] = mfma16(pf0, vf0, oacc[m][n]);
        oacc[m][n] = mfma16(pf1, vf1, oacc[m][n]);
      }
    }
    __syncthreads();
  }

#pragma unroll
  for (int m=0;m<2;++m)
#pragma unroll
    for (int n=0;n<4;++n)
#pragma unroll
      for (int r=0;r<4;++r){
        int row = q0 + wid*32 + m*16 + lg*4 + r;
        int col = hh*64 + n*16 + lr;
        float v = oacc[m][n][r] / lrun[m*4+r];
        ob[(size_t)row*DIM + col] = f2b(v);
      }
}

// ---------------- host ----------------
extern "C" void kernel_launch(void* const* d_in, const int* in_sizes, int n_in,
                              void* d_out, int out_size, void* d_ws, size_t ws_size,
                              hipStream_t stream)
{
  const float* x       = (const float*)d_in[0];
  const float* text    = (const float*)d_in[1];
  const float* w_embed = (const float*)d_in[2];
  const float* b_embed = (const float*)d_in[3];
  const float* w_text  = (const float*)d_in[4];
  const float* b_text  = (const float*)d_in[5];
  const float* ln1_w   = (const float*)d_in[6];
  const float* ln1_b   = (const float*)d_in[7];
  const float* qkv_w   = (const float*)d_in[8];
  const float* qkv_b   = (const float*)d_in[9];
  const float* proj_w  = (const float*)d_in[10];
  const float* proj_b  = (const float*)d_in[11];
  const float* ln2_w   = (const float*)d_in[12];
  const float* ln2_b   = (const float*)d_in[13];
  const float* fc1_w   = (const float*)d_in[14];
  const float* fc1_b   = (const float*)d_in[15];
  const float* fc2_w   = (const float*)d_in[16];
  const float* fc2_b   = (const float*)d_in[17];
  const float* normf_w = (const float*)d_in[18];
  const float* normf_b = (const float*)d_in[19];
  const float* w_out   = (const float*)d_in[20];
  const float* b_out   = (const float*)d_in[21];
  (void)in_sizes; (void)n_in; (void)out_size;

  char* ws = (char*)d_ws;
  size_t off = 0;
  auto alloc = [&](size_t bytes)->void*{
    void* p = ws + off; off += (bytes + 255) & ~(size_t)255; return p;
  };
  u16* wTe  = (u16*)alloc((size_t)1024*768*2);
  u16* wTt  = (u16*)alloc((size_t)1024*4096*2);
  u16* wTq  = (u16*)alloc((size_t)4*3072*1024*2);
  u16* wTp  = (u16*)alloc((size_t)4*1024*1024*2);
  u16* wT1  = (u16*)alloc((size_t)4*4096*1024*2);
  u16* wT2  = (u16*)alloc((size_t)4*1024*4096*2);
  u16* wTo  = (u16*)alloc((size_t)768*1024*2);
  u16* xbf  = (u16*)alloc((size_t)MPAD*768*2);
  u16* tbf  = (u16*)alloc((size_t)128*4096*2);
  float* h  = (float*)alloc((size_t)MPAD*1024*4);
  u16* lno  = (u16*)alloc((size_t)MPAD*1024*2);
  float* qkv= (float*)alloc((size_t)MPAD*3072*4);
  u16* qbuf = (u16*)alloc((size_t)HEADS*MPAD*64*2);
  u16* kbuf = (u16*)alloc((size_t)HEADS*MPAD*64*2);
  u16* vbuf = (u16*)alloc((size_t)HEADS*MPAD*64*2);
  u16* obf  = (u16*)alloc((size_t)MPAD*1024*2);
  u16* mlp  = (u16*)alloc((size_t)MPAD*4096*2);
  float* ct = (float*)alloc((size_t)NTOK*64*4);
  float* st = (float*)alloc((size_t)NTOK*64*4);
  if (off > ws_size) return;   // workspace too small: fail loudly (wrong output)

  // weights -> transposed bf16
  wtrans_kernel<<<dim3(1024/32, 768/32), 256, 0, stream>>>(w_embed, wTe, 768, 1024);
  wtrans_kernel<<<dim3(1024/32, 4096/32), 256, 0, stream>>>(w_text, wTt, 4096, 1024);
  for (int l=0;l<4;++l){
    wtrans_kernel<<<dim3(3072/32, 1024/32),256,0,stream>>>(qkv_w + (size_t)l*1024*3072, wTq + (size_t)l*3072*1024, 1024, 3072);
    wtrans_kernel<<<dim3(1024/32, 1024/32),256,0,stream>>>(proj_w + (size_t)l*1024*1024, wTp + (size_t)l*1024*1024, 1024, 1024);
    wtrans_kernel<<<dim3(4096/32, 1024/32),256,0,stream>>>(fc1_w + (size_t)l*1024*4096, wT1 + (size_t)l*4096*1024, 1024, 4096);
    wtrans_kernel<<<dim3(1024/32, 4096/32),256,0,stream>>>(fc2_w + (size_t)l*4096*1024, wT2 + (size_t)l*1024*4096, 4096, 1024);
  }
  wtrans_kernel<<<dim3(768/32, 1024/32),256,0,stream>>>(w_out, wTo, 1024, 768);

  f2b_kernel<<<(F_TOK*768+255)/256,256,0,stream>>>(x, xbf, F_TOK*768);
  f2b_kernel<<<(16*4096+255)/256,256,0,stream>>>(text, tbf, 16*4096);
  rope_table_kernel<<<(NTOK*64+255)/256,256,0,stream>>>(ct, st);

  // embed
  gemm_kernel<0><<<dim3(1024/128, 1),256,0,stream>>>(tbf, wTt, b_text, nullptr, h, nullptr, 16, 1024, 4096);
  gemm_kernel<0><<<dim3(1024/128, 13),256,0,stream>>>(xbf, wTe, b_embed, nullptr, h + (size_t)16*1024, nullptr, 1568, 1024, 768);

  for (int l=0;l<4;++l){
    ln_kernel<<<MPAD,256,0,stream>>>(h, ln1_w + l*1024, ln1_b + l*1024, lno);
    gemm_kernel<0><<<dim3(3072/128,13),256,0,stream>>>(lno, wTq + (size_t)l*3072*1024, qkv_b + l*3072, nullptr, qkv, nullptr, MPAD, 3072, 1024);
    rope_apply_kernel<<<(NTOK*512+255)/256,256,0,stream>>>(qkv, ct, st, qbuf, kbuf, vbuf);
    attn_kernel<<<dim3(13,16),256,0,stream>>>(qbuf, kbuf, vbuf, obf);
    gemm_kernel<2><<<dim3(1024/128,13),256,0,stream>>>(obf, wTp + (size_t)l*1024*1024, proj_b + l*1024, h, h, nullptr, MPAD, 1024, 1024);
    ln_kernel<<<MPAD,256,0,stream>>>(h, ln2_w + l*1024, ln2_b + l*1024, lno);
    gemm_kernel<3><<<dim3(4096/128,13),256,0,stream>>>(lno, wT1 + (size_t)l*4096*1024, fc1_b + l*4096, nullptr, nullptr, mlp, MPAD, 4096, 1024);
    gemm_kernel<2><<<dim3(1024/128,13),256,0,stream>>>(mlp, wT2 + (size_t)l*1024*4096, fc2_b + l*1024, h, h, nullptr, MPAD, 1024, 4096);
  }

  ln_kernel<<<F_TOK,256,0,stream>>>(h + (size_t)16*1024, normf_w, normf_b, lno);
  gemm_kernel<0><<<dim3(768/128,13),256,0,stream>>>(lno, wTo, b_out, nullptr, (float*)d_out, nullptr, F_TOK, 768, 1024);
}

// Round 3
// 1180.093 us; speedup vs baseline: 1.4376x; 1.4376x over previous
//
#include <hip/hip_runtime.h>
#include <hip/hip_bf16.h>
#include <math.h>

#define HEADS 16
#define DIM 1024
#define N_TEXT 16
#define F_TOK 1568
#define NTOK 1584
#define MPAD 1664
#define SCALEF 0.125f

typedef unsigned int uint;
typedef unsigned short u16;

typedef __bf16 bf16x8 __attribute__((ext_vector_type(8)));
typedef float f32x4 __attribute__((ext_vector_type(4)));

__device__ inline u16 f2b(float f){
  uint u = __builtin_bit_cast(uint, f);
  uint r = u + 0x7fffu + ((u >> 16) & 1u);
  return (u16)(r >> 16);
}

__device__ inline f32x4 mfma16(bf16x8 a, bf16x8 b, f32x4 c){
  return __builtin_amdgcn_mfma_f32_16x16x32_bf16(a, b, c, 0, 0, 0);
}

__device__ __forceinline__ void gload16(const u16* g, u16* l){
  __builtin_amdgcn_global_load_lds(
      (__attribute__((address_space(1))) u16*)const_cast<u16*>(g),
      (__attribute__((address_space(3))) u16*)l, 16, 0, 0);
}

// ---------------- weight transpose fp32[K][N] -> bf16[N][K] ----------------
__global__ __launch_bounds__(256) void wtrans_kernel(const float* __restrict__ src,
                                                     u16* __restrict__ dst, int K, int N){
  __shared__ float tile[32][33];
  int n0 = blockIdx.x * 32, k0 = blockIdx.y * 32;
  int t = threadIdx.x;
  int col = t & 31, rb = t >> 5;
#pragma unroll
  for (int p = 0; p < 4; ++p){
    int row = p*8 + rb;
    tile[row][col] = src[(size_t)(k0+row)*N + n0 + col];
  }
  __syncthreads();
#pragma unroll
  for (int p = 0; p < 4; ++p){
    int rn = p*8 + rb;
    dst[(size_t)(n0+rn)*K + k0 + col] = f2b(tile[col][rn]);
  }
}

// ---------------- flat fp32 -> bf16 ----------------
__global__ __launch_bounds__(256) void f2b_kernel(const float* __restrict__ src,
                                                  u16* __restrict__ dst, int n){
  int i = blockIdx.x*256 + threadIdx.x;
  if (i < n) dst[i] = f2b(src[i]);
}

// ---------------- rope tables ----------------
__global__ __launch_bounds__(256) void rope_table_kernel(float* __restrict__ ct,
                                                         float* __restrict__ st){
  int i = blockIdx.x*256 + threadIdx.x;
  if (i >= NTOK*64) return;
  int n = i >> 6, d = i & 63;
  float f = 0.f;
  if (n >= N_TEXT){
    int id = n - N_TEXT;
    int p0 = id / 196;
    int p1 = (id % 196) / 14;
    int p2 = id % 14;
    float pos = 0.f; int j = -1;
    if (d < 20){ pos = (float)p0; j = d >> 1; }
    else if (d < 40){ pos = (float)p1; j = (d-20) >> 1; }
    else if (d < 60){ pos = (float)p2; j = (d-40) >> 1; }
    if (j >= 0){
      float inv = powf(10000.f, -(float)j * 0.1f);
      f = pos * inv;
    }
  }
  ct[i] = cosf(f);
  st[i] = sinf(f);
}

// ---------------- rope apply + split qkv -> per-head bf16 ----------------
__global__ __launch_bounds__(256) void rope_apply_kernel(const float* __restrict__ qkv,
    const float* __restrict__ ct, const float* __restrict__ st,
    u16* __restrict__ qb, u16* __restrict__ kb, u16* __restrict__ vb){
  int i = blockIdx.x*256 + threadIdx.x;       // NTOK*16*32
  if (i >= NTOK*HEADS*32) return;
  int n = i / 512;
  int rem = i & 511;
  int h = rem >> 5;
  int d0 = (rem & 31) * 2;
  size_t base = (size_t)n*3072 + h*64 + d0;
  float q0 = qkv[base],      q1 = qkv[base+1];
  float k0 = qkv[base+1024], k1 = qkv[base+1025];
  float v0 = qkv[base+2048], v1 = qkv[base+2049];
  float c = ct[n*64+d0], s = st[n*64+d0];
  size_t ob = ((size_t)h*MPAD + n)*64 + d0;
  qb[ob]   = f2b(q0*c - q1*s);
  qb[ob+1] = f2b(q1*c + q0*s);
  kb[ob]   = f2b(k0*c - k1*s);
  kb[ob+1] = f2b(k1*c + k0*s);
  vb[ob]   = f2b(v0);
  vb[ob+1] = f2b(v1);
}

// ---------------- layernorm (fp32 in, bf16 out) ----------------
__global__ __launch_bounds__(256) void ln_kernel(const float* __restrict__ x,
    const float* __restrict__ w, const float* __restrict__ b, u16* __restrict__ out){
  int row = blockIdx.x, t = threadIdx.x;
  const float* xr = x + (size_t)row * DIM;
  float4 v = *(const float4*)&xr[t*4];
  float s = v.x+v.y+v.z+v.w;
  float ss = v.x*v.x+v.y*v.y+v.z*v.z+v.w*v.w;
#pragma unroll
  for (int o=32;o>0;o>>=1){ s += __shfl_down(s,o,64); ss += __shfl_down(ss,o,64); }
  __shared__ float red[8];
  int wid = t>>6;
  if ((t&63)==0){ red[wid] = s; red[4+wid] = ss; }
  __syncthreads();
  float S = red[0]+red[1]+red[2]+red[3];
  float SS = red[4]+red[5]+red[6]+red[7];
  float mean = S * (1.0f/1024.0f);
  float var = SS * (1.0f/1024.0f) - mean*mean;
  float inv = rsqrtf(var + 1e-5f);
  ushort4 o4;
  o4.x = f2b((v.x-mean)*inv*w[t*4+0]+b[t*4+0]);
  o4.y = f2b((v.y-mean)*inv*w[t*4+1]+b[t*4+1]);
  o4.z = f2b((v.z-mean)*inv*w[t*4+2]+b[t*4+2]);
  o4.w = f2b((v.w-mean)*inv*w[t*4+3]+b[t*4+3]);
  *(ushort4*)&out[(size_t)row*DIM + t*4] = o4;
}

// ================= pipelined bf16 MFMA GEMM =================
// C = A[M][K] @ BT[N][K]^T ; 128x128 tile, BK=64, double-buffered LDS via
// global_load_lds (linear dest) + XOR-swizzled source/read (slot ^= row&7).
// EPI: 0 = +bias -> fp32 ; 3 = +bias,gelu -> bf16 ; 4 = raw partial fp32 (split-K)
template<int EPI>
__global__ __launch_bounds__(256, 2)
void gemm2_kernel(const u16* __restrict__ A, const u16* __restrict__ BT,
                  const float* __restrict__ bias,
                  float* __restrict__ outF, u16* __restrict__ outB,
                  int M, int N, int K, int klen, size_t partStride)
{
  __shared__ u16 L[2][2][128*64];   // [buf][A/B][row*64 + swizzled slot]
  const int t = threadIdx.x, wid = t >> 6, lane = t & 63;
  const int lr = lane & 15, lg = lane >> 4;
  const int wr = wid >> 1, wc = wid & 1;
  const int m0 = blockIdx.y * 128, n0 = blockIdx.x * 128;
  const int kstart = blockIdx.z * klen;

  // staging: chunk c = wid*4+j covers rows c*8..c*8+7; lane covers (row, slot)
  const int srow = lane >> 3;
  const int scol = ((lane & 7) ^ srow) * 8;          // inverse-swizzled source column
  const u16* Ast = A  + (size_t)(m0 + srow)*K + kstart + scol;
  const u16* Bst = BT + (size_t)(n0 + srow)*K + kstart + scol;

  // swizzled read slots (involution: same XOR as source)
  const int s0 = (lg     ) ^ (lr & 7);
  const int s1 = (lg + 4 ) ^ (lr & 7);
  const int aBase = (wr*64 + lr)*64;
  const int bBase = (wc*64 + lr)*64;

  f32x4 acc[4][4] = {};
  const int nk = klen >> 6;

  auto STAGE = [&](int buf, int step){
    const u16* a = Ast + (size_t)step*64;
    const u16* b = Bst + (size_t)step*64;
#pragma unroll
    for (int j = 0; j < 4; ++j){
      int c = wid*4 + j;
      gload16(a + (size_t)c*8*K, &L[buf][0][c*512]);
      gload16(b + (size_t)c*8*K, &L[buf][1][c*512]);
    }
  };

  STAGE(0, 0);
  __syncthreads();
  int cur = 0;
  for (int tt = 0; tt < nk; ++tt){
    if (tt + 1 < nk) STAGE(cur ^ 1, tt + 1);
    const u16* Ab = &L[cur][0][0];
    const u16* Bb = &L[cur][1][0];
    bf16x8 af[2][4], bv[2][4];
#pragma unroll
    for (int m = 0; m < 4; ++m){
      af[0][m] = *(const bf16x8*)&Ab[aBase + m*1024 + s0*8];
      af[1][m] = *(const bf16x8*)&Ab[aBase + m*1024 + s1*8];
    }
#pragma unroll
    for (int n = 0; n < 4; ++n){
      bv[0][n] = *(const bf16x8*)&Bb[bBase + n*1024 + s0*8];
      bv[1][n] = *(const bf16x8*)&Bb[bBase + n*1024 + s1*8];
    }
#pragma unroll
    for (int ks = 0; ks < 2; ++ks)
#pragma unroll
      for (int m = 0; m < 4; ++m)
#pragma unroll
        for (int n = 0; n < 4; ++n)
          acc[m][n] = mfma16(af[ks][m], bv[ks][n], acc[m][n]);
    __syncthreads();
    cur ^= 1;
  }

#pragma unroll
  for (int m = 0; m < 4; ++m){
#pragma unroll
    for (int r = 0; r < 4; ++r){
      int row = m0 + wr*64 + m*16 + lg*4 + r;
      if (row >= M) continue;
#pragma unroll
      for (int n = 0; n < 4; ++n){
        int col = n0 + wc*64 + n*16 + lr;
        float v = acc[m][n][r];
        if constexpr (EPI == 4){
          outF[partStride*blockIdx.z + (size_t)row*N + col] = v;
        } else if constexpr (EPI == 3){
          v += bias[col];
          v = 0.5f * v * (1.0f + erff(v * 0.70710678118654752f));
          outB[(size_t)row*N + col] = f2b(v);
        } else {
          v += bias[col];
          outF[(size_t)row*N + col] = v;
        }
      }
    }
  }
}

// ---------------- split-K reduce: out = bias + (resid?) + sum_s part[s] ----------------
__global__ __launch_bounds__(256) void reduce_kernel(const float* __restrict__ part,
    size_t stride, int S, const float* __restrict__ bias, const float* __restrict__ resid,
    float* __restrict__ out, int MN, int N){
  int i = (blockIdx.x*256 + threadIdx.x)*4;
  if (i >= MN) return;
  float4 v = *(const float4*)&bias[i % N];
  if (resid){
    float4 r = *(const float4*)&resid[i];
    v.x += r.x; v.y += r.y; v.z += r.z; v.w += r.w;
  }
  for (int s = 0; s < S; ++s){
    float4 p = *(const float4*)&part[(size_t)s*stride + i];
    v.x += p.x; v.y += p.y; v.z += p.z; v.w += p.w;
  }
  *(float4*)&out[i] = v;
}

// ---------------- attention mask bias ----------------
__device__ inline float bias_fn(int qi, int ki){
  if (ki >= NTOK) return -1e9f;
  if (qi < N_TEXT) return (ki <= qi) ? 0.f : -1e9f;
  if (ki < N_TEXT) return 0.f;
  int fq = (qi - N_TEXT) / 196;
  int fk = (ki - N_TEXT) / 196;
  return (fk <= fq) ? 0.f : -1e9f;
}

// ---------------- fused flash attention: per (q-block 128, head) ----------------
__global__ __launch_bounds__(256)
void attn_kernel(const u16* __restrict__ qb, const u16* __restrict__ kb,
                 const u16* __restrict__ vb, u16* __restrict__ ob)
{
  __shared__ u16 Kl[64][72];
  __shared__ u16 Vl[64][72];
  __shared__ u16 Pl[128][72];
  const int hh = blockIdx.y;
  const int q0 = blockIdx.x * 128;
  const int t = threadIdx.x, wid = t>>6, lane = t&63, lr = lane&15, lg = lane>>4;

  bf16x8 qf[2][2];
#pragma unroll
  for (int m=0;m<2;++m)
#pragma unroll
    for (int ks=0;ks<2;++ks){
      int row = q0 + wid*32 + m*16 + lr;
      qf[m][ks] = *(const bf16x8*)&qb[((size_t)hh*MPAD + row)*64 + ks*32 + lg*8];
    }

  float mrun[8], lrun[8];
#pragma unroll
  for (int i=0;i<8;++i){ mrun[i] = -3.0e38f; lrun[i] = 0.0f; }
  f32x4 oacc[2][4] = {};

  for (int kbi = 0; kbi < 25; ++kbi){
    int k0 = kbi*64;
#pragma unroll
    for (int p=0;p<2;++p){
      int sidx = t + p*256;
      int row = sidx >> 3, c8 = (sidx & 7) * 8;
      *(uint4*)&Kl[row][c8] = *(const uint4*)&kb[((size_t)hh*MPAD + k0 + row)*64 + c8];
    }
#pragma unroll
    for (int p=0;p<2;++p){
      int sidx = t + p*256;
      int kk = sidx & 63, d8 = (sidx >> 6) * 8;
      union { uint4 u; u16 s[8]; } tv;
      tv.u = *(const uint4*)&vb[((size_t)hh*MPAD + k0 + kk)*64 + d8];
#pragma unroll
      for (int j=0;j<8;++j) Vl[d8+j][kk] = tv.s[j];
    }
    __syncthreads();

    f32x4 sacc[2][4] = {};
#pragma unroll
    for (int n=0;n<4;++n){
      bf16x8 kf0 = *(const bf16x8*)&Kl[n*16 + lr][lg*8];
      bf16x8 kf1 = *(const bf16x8*)&Kl[n*16 + lr][32 + lg*8];
#pragma unroll
      for (int m=0;m<2;++m){
        sacc[m][n] = mfma16(qf[m][0], kf0, sacc[m][n]);
        sacc[m][n] = mfma16(qf[m][1], kf1, sacc[m][n]);
      }
    }

    float sval[2][4][4];
    float pmax[8];
#pragma unroll
    for (int i=0;i<8;++i) pmax[i] = -3.0e38f;
#pragma unroll
    for (int m=0;m<2;++m)
#pragma unroll
      for (int n=0;n<4;++n)
#pragma unroll
        for (int r=0;r<4;++r){
          int qi = q0 + wid*32 + m*16 + lg*4 + r;
          int ki = k0 + n*16 + lr;
          float v = sacc[m][n][r]*SCALEF + bias_fn(qi, ki);
          sval[m][n][r] = v;
          pmax[m*4+r] = fmaxf(pmax[m*4+r], v);
        }
#pragma unroll
    for (int i=0;i<8;++i){
      float v = pmax[i];
      v = fmaxf(v, __shfl_xor(v,1,64));
      v = fmaxf(v, __shfl_xor(v,2,64));
      v = fmaxf(v, __shfl_xor(v,4,64));
      v = fmaxf(v, __shfl_xor(v,8,64));
      pmax[i] = v;
    }
    float alpha[8], psum[8];
#pragma unroll
    for (int i=0;i<8;++i){
      float mnew = fmaxf(mrun[i], pmax[i]);
      alpha[i] = expf(mrun[i] - mnew);
      mrun[i] = mnew;
      psum[i] = 0.f;
    }
#pragma unroll
    for (int m=0;m<2;++m)
#pragma unroll
      for (int r=0;r<4;++r){
        float mn = mrun[m*4+r];
#pragma unroll
        for (int n=0;n<4;++n){
          float p = expf(sval[m][n][r] - mn);
          psum[m*4+r] += p;
          Pl[wid*32 + m*16 + lg*4 + r][n*16 + lr] = f2b(p);
        }
      }
#pragma unroll
    for (int i=0;i<8;++i){
      float v = psum[i];
      v += __shfl_xor(v,1,64); v += __shfl_xor(v,2,64);
      v += __shfl_xor(v,4,64); v += __shfl_xor(v,8,64);
      lrun[i] = lrun[i]*alpha[i] + v;
    }
#pragma unroll
    for (int m=0;m<2;++m)
#pragma unroll
      for (int n=0;n<4;++n)
#pragma unroll
        for (int r=0;r<4;++r)
          oacc[m][n][r] *= alpha[m*4+r];
    __syncthreads();

#pragma unroll
    for (int m=0;m<2;++m){
      bf16x8 pf0 = *(const bf16x8*)&Pl[wid*32 + m*16 + lr][lg*8];
      bf16x8 pf1 = *(const bf16x8*)&Pl[wid*32 + m*16 + lr][32 + lg*8];
#pragma unroll
      for (int n=0;n<4;++n){
        bf16x8 vf0 = *(const bf16x8*)&Vl[n*16 + lr][lg*8];
        bf16x8 vf1 = *(const bf16x8*)&Vl[n*16 + lr][32 + lg*8];
        oacc[m][n] = mfma16(pf0, vf0, oacc[m][n]);
        oacc[m][n] = mfma16(pf1, vf1, oacc[m][n]);
      }
    }
    __syncthreads();
  }

#pragma unroll
  for (int m=0;m<2;++m)
#pragma unroll
    for (int n=0;n<4;++n)
#pragma unroll
      for (int r=0;r<4;++r){
        int row = q0 + wid*32 + m*16 + lg*4 + r;
        int col = hh*64 + n*16 + lr;
        float v = oacc[m][n][r] / lrun[m*4+r];
        ob[(size_t)row*DIM + col] = f2b(v);
      }
}

// ---------------- host ----------------
extern "C" void kernel_launch(void* const* d_in, const int* in_sizes, int n_in,
                              void* d_out, int out_size, void* d_ws, size_t ws_size,
                              hipStream_t stream)
{
  const float* x       = (const float*)d_in[0];
  const float* text    = (const float*)d_in[1];
  const float* w_embed = (const float*)d_in[2];
  const float* b_embed = (const float*)d_in[3];
  const float* w_text  = (const float*)d_in[4];
  const float* b_text  = (const float*)d_in[5];
  const float* ln1_w   = (const float*)d_in[6];
  const float* ln1_b   = (const float*)d_in[7];
  const float* qkv_w   = (const float*)d_in[8];
  const float* qkv_b   = (const float*)d_in[9];
  const float* proj_w  = (const float*)d_in[10];
  const float* proj_b  = (const float*)d_in[11];
  const float* ln2_w   = (const float*)d_in[12];
  const float* ln2_b   = (const float*)d_in[13];
  const float* fc1_w   = (const float*)d_in[14];
  const float* fc1_b   = (const float*)d_in[15];
  const float* fc2_w   = (const float*)d_in[16];
  const float* fc2_b   = (const float*)d_in[17];
  const float* normf_w = (const float*)d_in[18];
  const float* normf_b = (const float*)d_in[19];
  const float* w_out   = (const float*)d_in[20];
  const float* b_out   = (const float*)d_in[21];
  (void)in_sizes; (void)n_in; (void)out_size;

  char* ws = (char*)d_ws;
  size_t off = 0;
  auto alloc = [&](size_t bytes)->void*{
    void* p = ws + off; off += (bytes + 255) & ~(size_t)255; return p;
  };
  u16* wTe  = (u16*)alloc((size_t)1024*768*2);
  u16* wTt  = (u16*)alloc((size_t)1024*4096*2);
  u16* wTq  = (u16*)alloc((size_t)4*3072*1024*2);
  u16* wTp  = (u16*)alloc((size_t)4*1024*1024*2);
  u16* wT1  = (u16*)alloc((size_t)4*4096*1024*2);
  u16* wT2  = (u16*)alloc((size_t)4*1024*4096*2);
  u16* wTo  = (u16*)alloc((size_t)768*1024*2);
  u16* xbf  = (u16*)alloc((size_t)MPAD*768*2);
  u16* tbf  = (u16*)alloc((size_t)128*4096*2);
  float* h  = (float*)alloc((size_t)MPAD*1024*4);
  u16* lno  = (u16*)alloc((size_t)MPAD*1024*2);
  float* qkv= (float*)alloc((size_t)MPAD*3072*4);
  u16* qbuf = (u16*)alloc((size_t)HEADS*MPAD*64*2);
  u16* kbuf = (u16*)alloc((size_t)HEADS*MPAD*64*2);
  u16* vbuf = (u16*)alloc((size_t)HEADS*MPAD*64*2);
  u16* obf  = (u16*)alloc((size_t)MPAD*1024*2);
  u16* mlp  = (u16*)alloc((size_t)MPAD*4096*2);   // also aliases proj split-K partials (2 x MPAD x 1024 fp32)
  float* ct = (float*)alloc((size_t)NTOK*64*4);
  float* st = (float*)alloc((size_t)NTOK*64*4);
  float* partF = (float*)alloc((size_t)4*MPAD*1024*4);  // fc2 / out / text partials
  if (off > ws_size) return;
  float* projPart = (float*)mlp;

  // weights -> transposed bf16
  wtrans_kernel<<<dim3(1024/32, 768/32), 256, 0, stream>>>(w_embed, wTe, 768, 1024);
  wtrans_kernel<<<dim3(1024/32, 4096/32), 256, 0, stream>>>(w_text, wTt, 4096, 1024);
  for (int l=0;l<4;++l){
    wtrans_kernel<<<dim3(3072/32, 1024/32),256,0,stream>>>(qkv_w + (size_t)l*1024*3072, wTq + (size_t)l*3072*1024, 1024, 3072);
    wtrans_kernel<<<dim3(1024/32, 1024/32),256,0,stream>>>(proj_w + (size_t)l*1024*1024, wTp + (size_t)l*1024*1024, 1024, 1024);
    wtrans_kernel<<<dim3(4096/32, 1024/32),256,0,stream>>>(fc1_w + (size_t)l*1024*4096, wT1 + (size_t)l*4096*1024, 1024, 4096);
    wtrans_kernel<<<dim3(1024/32, 4096/32),256,0,stream>>>(fc2_w + (size_t)l*4096*1024, wT2 + (size_t)l*1024*4096, 4096, 1024);
  }
  wtrans_kernel<<<dim3(768/32, 1024/32),256,0,stream>>>(w_out, wTo, 1024, 768);

  f2b_kernel<<<(F_TOK*768+255)/256,256,0,stream>>>(x, xbf, F_TOK*768);
  f2b_kernel<<<(16*4096+255)/256,256,0,stream>>>(text, tbf, 16*4096);
  rope_table_kernel<<<(NTOK*64+255)/256,256,0,stream>>>(ct, st);

  // text embed: M=16, N=1024, K=4096, split-K S=8
  gemm2_kernel<4><<<dim3(8,1,8),256,0,stream>>>(tbf, wTt, nullptr, partF, nullptr,
      16, 1024, 4096, 512, (size_t)16*1024);
  reduce_kernel<<<(16*1024/4+255)/256,256,0,stream>>>(partF, (size_t)16*1024, 8, b_text, nullptr, h, 16*1024, 1024);
  // image embed: M=1568, N=1024, K=768
  gemm2_kernel<0><<<dim3(8,13,1),256,0,stream>>>(xbf, wTe, b_embed, h + (size_t)16*1024, nullptr,
      1568, 1024, 768, 768, 0);

  for (int l=0;l<4;++l){
    ln_kernel<<<MPAD,256,0,stream>>>(h, ln1_w + l*1024, ln1_b + l*1024, lno);
    gemm2_kernel<0><<<dim3(24,13,1),256,0,stream>>>(lno, wTq + (size_t)l*3072*1024, qkv_b + l*3072,
        qkv, nullptr, MPAD, 3072, 1024, 1024, 0);
    rope_apply_kernel<<<(NTOK*512+255)/256,256,0,stream>>>(qkv, ct, st, qbuf, kbuf, vbuf);
    attn_kernel<<<dim3(13,16),256,0,stream>>>(qbuf, kbuf, vbuf, obf);
    // proj: split-K S=2, partials alias mlp
    gemm2_kernel<4><<<dim3(8,13,2),256,0,stream>>>(obf, wTp + (size_t)l*1024*1024, nullptr,
        projPart, nullptr, MPAD, 1024, 1024, 512, (size_t)MPAD*1024);
    reduce_kernel<<<(MPAD*1024/4+255)/256,256,0,stream>>>(projPart, (size_t)MPAD*1024, 2,
        proj_b + l*1024, h, h, MPAD*1024, 1024);
    ln_kernel<<<MPAD,256,0,stream>>>(h, ln2_w + l*1024, ln2_b + l*1024, lno);
    gemm2_kernel<3><<<dim3(32,13,1),256,0,stream>>>(lno, wT1 + (size_t)l*4096*1024, fc1_b + l*4096,
        nullptr, mlp, MPAD, 4096, 1024, 1024, 0);
    // fc2: split-K S=4
    gemm2_kernel<4><<<dim3(8,13,4),256,0,stream>>>(mlp, wT2 + (size_t)l*1024*4096, nullptr,
        partF, nullptr, MPAD, 1024, 4096, 1024, (size_t)MPAD*1024);
    reduce_kernel<<<(MPAD*1024/4+255)/256,256,0,stream>>>(partF, (size_t)MPAD*1024, 4,
        fc2_b + l*1024, h, h, MPAD*1024, 1024);
  }

  ln_kernel<<<F_TOK,256,0,stream>>>(h + (size_t)16*1024, normf_w, normf_b, lno);
  // out: M=1568, N=768, K=1024, split-K S=4
  gemm2_kernel<4><<<dim3(6,13,4),256,0,stream>>>(lno, wTo, nullptr, partF, nullptr,
      F_TOK, 768, 1024, 256, (size_t)F_TOK*768);
  reduce_kernel<<<(F_TOK*768/4+255)/256,256,0,stream>>>(partF, (size_t)F_TOK*768, 4,
      b_out, nullptr, (float*)d_out, F_TOK*768, 768);
}

// Round 5
// 1066.638 us; speedup vs baseline: 1.5905x; 1.1064x over previous
//
#include <hip/hip_runtime.h>
#include <hip/hip_bf16.h>
#include <math.h>

#define HEADS 16
#define DIM 1024
#define N_TEXT 16
#define F_TOK 1568
#define NTOK 1584
#define MPAD 1664
#define SCALEF 0.125f

typedef unsigned int uint;
typedef unsigned short u16;

typedef __bf16 bf16x8 __attribute__((ext_vector_type(8)));
typedef float f32x4 __attribute__((ext_vector_type(4)));

__device__ inline u16 f2b(float f){
  uint u = __builtin_bit_cast(uint, f);
  uint r = u + 0x7fffu + ((u >> 16) & 1u);
  return (u16)(r >> 16);
}

__device__ inline f32x4 mfma16(bf16x8 a, bf16x8 b, f32x4 c){
  return __builtin_amdgcn_mfma_f32_16x16x32_bf16(a, b, c, 0, 0, 0);
}

__device__ __forceinline__ void gload16(const u16* g, u16* l){
  __builtin_amdgcn_global_load_lds(
      (__attribute__((address_space(1))) u16*)const_cast<u16*>(g),
      (__attribute__((address_space(3))) u16*)l, 16, 0, 0);
}

// ---------------- weight transpose fp32[K][N] -> bf16[N][K] ----------------
__global__ __launch_bounds__(256) void wtrans_kernel(const float* __restrict__ src,
                                                     u16* __restrict__ dst, int K, int N){
  __shared__ float tile[32][33];
  int n0 = blockIdx.x * 32, k0 = blockIdx.y * 32;
  int t = threadIdx.x;
  int col = t & 31, rb = t >> 5;
#pragma unroll
  for (int p = 0; p < 4; ++p){
    int row = p*8 + rb;
    tile[row][col] = src[(size_t)(k0+row)*N + n0 + col];
  }
  __syncthreads();
#pragma unroll
  for (int p = 0; p < 4; ++p){
    int rn = p*8 + rb;
    dst[(size_t)(n0+rn)*K + k0 + col] = f2b(tile[col][rn]);
  }
}

// ---------------- flat fp32 -> bf16 ----------------
__global__ __launch_bounds__(256) void f2b_kernel(const float* __restrict__ src,
                                                  u16* __restrict__ dst, int n){
  int i = blockIdx.x*256 + threadIdx.x;
  if (i < n) dst[i] = f2b(src[i]);
}

// ---------------- rope tables ----------------
__global__ __launch_bounds__(256) void rope_table_kernel(float* __restrict__ ct,
                                                         float* __restrict__ st){
  int i = blockIdx.x*256 + threadIdx.x;
  if (i >= NTOK*64) return;
  int n = i >> 6, d = i & 63;
  float f = 0.f;
  if (n >= N_TEXT){
    int id = n - N_TEXT;
    int p0 = id / 196;
    int p1 = (id % 196) / 14;
    int p2 = id % 14;
    float pos = 0.f; int j = -1;
    if (d < 20){ pos = (float)p0; j = d >> 1; }
    else if (d < 40){ pos = (float)p1; j = (d-20) >> 1; }
    else if (d < 60){ pos = (float)p2; j = (d-40) >> 1; }
    if (j >= 0){
      float inv = powf(10000.f, -(float)j * 0.1f);
      f = pos * inv;
    }
  }
  ct[i] = cosf(f);
  st[i] = sinf(f);
}

// ---------------- rope apply + split qkv -> per-head bf16 ----------------
__global__ __launch_bounds__(256) void rope_apply_kernel(const float* __restrict__ qkv,
    const float* __restrict__ ct, const float* __restrict__ st,
    u16* __restrict__ qb, u16* __restrict__ kb, u16* __restrict__ vb){
  int i = blockIdx.x*256 + threadIdx.x;       // NTOK*16*32
  if (i >= NTOK*HEADS*32) return;
  int n = i / 512;
  int rem = i & 511;
  int h = rem >> 5;
  int d0 = (rem & 31) * 2;
  size_t base = (size_t)n*3072 + h*64 + d0;
  float q0 = qkv[base],      q1 = qkv[base+1];
  float k0 = qkv[base+1024], k1 = qkv[base+1025];
  float v0 = qkv[base+2048], v1 = qkv[base+2049];
  float c = ct[n*64+d0], s = st[n*64+d0];
  size_t ob = ((size_t)h*MPAD + n)*64 + d0;
  qb[ob]   = f2b(q0*c - q1*s);
  qb[ob+1] = f2b(q1*c + q0*s);
  kb[ob]   = f2b(k0*c - k1*s);
  kb[ob+1] = f2b(k1*c + k0*s);
  vb[ob]   = f2b(v0);
  vb[ob+1] = f2b(v1);
}

// ---------------- layernorm (fp32 in, bf16 out) ----------------
__global__ __launch_bounds__(256) void ln_kernel(const float* __restrict__ x,
    const float* __restrict__ w, const float* __restrict__ b, u16* __restrict__ out){
  int row = blockIdx.x, t = threadIdx.x;
  const float* xr = x + (size_t)row * DIM;
  float4 v = *(const float4*)&xr[t*4];
  float s = v.x+v.y+v.z+v.w;
  float ss = v.x*v.x+v.y*v.y+v.z*v.z+v.w*v.w;
#pragma unroll
  for (int o=32;o>0;o>>=1){ s += __shfl_down(s,o,64); ss += __shfl_down(ss,o,64); }
  __shared__ float red[8];
  int wid = t>>6;
  if ((t&63)==0){ red[wid] = s; red[4+wid] = ss; }
  __syncthreads();
  float S = red[0]+red[1]+red[2]+red[3];
  float SS = red[4]+red[5]+red[6]+red[7];
  float mean = S * (1.0f/1024.0f);
  float var = SS * (1.0f/1024.0f) - mean*mean;
  float inv = rsqrtf(var + 1e-5f);
  ushort4 o4;
  o4.x = f2b((v.x-mean)*inv*w[t*4+0]+b[t*4+0]);
  o4.y = f2b((v.y-mean)*inv*w[t*4+1]+b[t*4+1]);
  o4.z = f2b((v.z-mean)*inv*w[t*4+2]+b[t*4+2]);
  o4.w = f2b((v.w-mean)*inv*w[t*4+3]+b[t*4+3]);
  *(ushort4*)&out[(size_t)row*DIM + t*4] = o4;
}

// ================= pipelined bf16 MFMA GEMM =================
// C = A[M][K] @ BT[N][K]^T ; 128x128 tile, BK=64, double-buffered LDS via
// global_load_lds (linear dest) + XOR-swizzled source/read (slot ^= row&7).
// EPI: 0 = +bias -> fp32 ; 3 = +bias,gelu -> bf16 ; 4 = raw partial fp32 (split-K)
template<int EPI>
__global__ __launch_bounds__(256, 2)
void gemm2_kernel(const u16* __restrict__ A, const u16* __restrict__ BT,
                  const float* __restrict__ bias,
                  float* __restrict__ outF, u16* __restrict__ outB,
                  int M, int N, int K, int klen, size_t partStride)
{
  __shared__ u16 L[2][2][128*64];   // [buf][A/B][row*64 + swizzled slot]
  const int t = threadIdx.x, wid = t >> 6, lane = t & 63;
  const int lr = lane & 15, lg = lane >> 4;
  const int wr = wid >> 1, wc = wid & 1;
  const int m0 = blockIdx.y * 128, n0 = blockIdx.x * 128;
  const int kstart = blockIdx.z * klen;

  // staging: chunk c = wid*4+j covers rows c*8..c*8+7; lane covers (row, slot)
  const int srow = lane >> 3;
  const int scol = ((lane & 7) ^ srow) * 8;          // inverse-swizzled source column
  const u16* Ast = A  + (size_t)(m0 + srow)*K + kstart + scol;
  const u16* Bst = BT + (size_t)(n0 + srow)*K + kstart + scol;

  // swizzled read slots (involution: same XOR as source)
  const int s0 = (lg     ) ^ (lr & 7);
  const int s1 = (lg + 4 ) ^ (lr & 7);
  const int aBase = (wr*64 + lr)*64;
  const int bBase = (wc*64 + lr)*64;

  f32x4 acc[4][4] = {};
  const int nk = klen >> 6;

  auto STAGE = [&](int buf, int step){
    const u16* a = Ast + (size_t)step*64;
    const u16* b = Bst + (size_t)step*64;
#pragma unroll
    for (int j = 0; j < 4; ++j){
      int c = wid*4 + j;
      gload16(a + (size_t)c*8*K, &L[buf][0][c*512]);
      gload16(b + (size_t)c*8*K, &L[buf][1][c*512]);
    }
  };

  STAGE(0, 0);
  __syncthreads();
  int cur = 0;
  for (int tt = 0; tt < nk; ++tt){
    if (tt + 1 < nk) STAGE(cur ^ 1, tt + 1);
    const u16* Ab = &L[cur][0][0];
    const u16* Bb = &L[cur][1][0];
    bf16x8 af[2][4], bv[2][4];
#pragma unroll
    for (int m = 0; m < 4; ++m){
      af[0][m] = *(const bf16x8*)&Ab[aBase + m*1024 + s0*8];
      af[1][m] = *(const bf16x8*)&Ab[aBase + m*1024 + s1*8];
    }
#pragma unroll
    for (int n = 0; n < 4; ++n){
      bv[0][n] = *(const bf16x8*)&Bb[bBase + n*1024 + s0*8];
      bv[1][n] = *(const bf16x8*)&Bb[bBase + n*1024 + s1*8];
    }
#pragma unroll
    for (int ks = 0; ks < 2; ++ks)
#pragma unroll
      for (int m = 0; m < 4; ++m)
#pragma unroll
        for (int n = 0; n < 4; ++n)
          acc[m][n] = mfma16(af[ks][m], bv[ks][n], acc[m][n]);
    __syncthreads();
    cur ^= 1;
  }

#pragma unroll
  for (int m = 0; m < 4; ++m){
#pragma unroll
    for (int r = 0; r < 4; ++r){
      int row = m0 + wr*64 + m*16 + lg*4 + r;
      if (row >= M) continue;
#pragma unroll
      for (int n = 0; n < 4; ++n){
        int col = n0 + wc*64 + n*16 + lr;
        float v = acc[m][n][r];
        if constexpr (EPI == 4){
          outF[partStride*blockIdx.z + (size_t)row*N + col] = v;
        } else if constexpr (EPI == 3){
          v += bias[col];
          v = 0.5f * v * (1.0f + erff(v * 0.70710678118654752f));
          outB[(size_t)row*N + col] = f2b(v);
        } else {
          v += bias[col];
          outF[(size_t)row*N + col] = v;
        }
      }
    }
  }
}

// ---------------- split-K reduce: out = bias + (resid?) + sum_s part[s] ----------------
__global__ __launch_bounds__(256) void reduce_kernel(const float* __restrict__ part,
    size_t stride, int S, const float* __restrict__ bias, const float* __restrict__ resid,
    float* __restrict__ out, int MN, int N){
  int i = (blockIdx.x*256 + threadIdx.x)*4;
  if (i >= MN) return;
  float4 v = *(const float4*)&bias[i % N];
  if (resid){
    float4 r = *(const float4*)&resid[i];
    v.x += r.x; v.y += r.y; v.z += r.z; v.w += r.w;
  }
  for (int s = 0; s < S; ++s){
    float4 p = *(const float4*)&part[(size_t)s*stride + i];
    v.x += p.x; v.y += p.y; v.z += p.z; v.w += p.w;
  }
  *(float4*)&out[i] = v;
}

// ---------------- fused flash attention ----------------
// Mask is a pure threshold: allowed(qi,ki) <=> ki < limit(qi),
//   limit(qi) = qi<16 ? qi+1 : 16 + ((qi-16)/196 + 1)*196   (monotone in qi)
// => skip k-tiles past limit(last row of block); per-element mask = 1 compare.
// One block per (64 q-rows, head); wave w owns rows q0+w*16..+15.
__global__ __launch_bounds__(256)
void attn_kernel(const u16* __restrict__ qb, const u16* __restrict__ kb,
                 const u16* __restrict__ vb, u16* __restrict__ ob)
{
  __shared__ u16 Kl[64][72];
  __shared__ u16 Vl[64][72];    // V^T: [d][kk]
  __shared__ u16 Pl[64][72];
  const int hh = blockIdx.y;
  const int q0 = blockIdx.x * 64;
  const int t = threadIdx.x, wid = t>>6, lane = t&63, lr = lane&15, lg = lane>>4;
  const size_t hbase = (size_t)hh*MPAD*64;

  bf16x8 qf[2];
  {
    int row = q0 + wid*16 + lr;
    qf[0] = *(const bf16x8*)&qb[hbase + (size_t)row*64 + lg*8];
    qf[1] = *(const bf16x8*)&qb[hbase + (size_t)row*64 + 32 + lg*8];
  }

  // per-thread row limits (rows qi = q0 + wid*16 + lg*4 + r)
  int lim[4];
#pragma unroll
  for (int r=0;r<4;++r){
    int qi = q0 + wid*16 + lg*4 + r;
    int L = (qi < N_TEXT) ? (qi + 1) : (16 + ((qi - 16)/196 + 1)*196);
    lim[r] = min(L, NTOK);
  }
  const int qlast = min(q0 + 63, NTOK - 1);
  const int kend  = (qlast < N_TEXT) ? (qlast + 1)
                                     : min(16 + ((qlast - 16)/196 + 1)*196, NTOK);
  const int nkt = (kend + 63) >> 6;

  float mrun[4], lrun[4];
#pragma unroll
  for (int i=0;i<4;++i){ mrun[i] = -3.0e38f; lrun[i] = 0.0f; }
  f32x4 oacc[4] = {};

  for (int kbi = 0; kbi < nkt; ++kbi){
    const int k0 = kbi*64;
#pragma unroll
    for (int p=0;p<2;++p){                  // stage K: 64 rows x 64 d
      int sidx = t + p*256;
      int row = sidx >> 3, c8 = (sidx & 7) * 8;
      *(uint4*)&Kl[row][c8] = *(const uint4*)&kb[hbase + (size_t)(k0 + row)*64 + c8];
    }
#pragma unroll
    for (int p=0;p<2;++p){                  // stage V^T
      int sidx = t + p*256;
      int kk = sidx & 63, d8 = (sidx >> 6) * 8;
      union { uint4 u; u16 s[8]; } tv;
      tv.u = *(const uint4*)&vb[hbase + (size_t)(k0 + kk)*64 + d8];
#pragma unroll
      for (int j=0;j<8;++j) Vl[d8+j][kk] = tv.s[j];
    }
    __syncthreads();

    // QK^T: 16 q-rows x 64 keys per wave
    f32x4 sacc[4] = {};
#pragma unroll
    for (int n=0;n<4;++n){
      bf16x8 kf0 = *(const bf16x8*)&Kl[n*16 + lr][lg*8];
      bf16x8 kf1 = *(const bf16x8*)&Kl[n*16 + lr][32 + lg*8];
      sacc[n] = mfma16(qf[0], kf0, sacc[n]);
      sacc[n] = mfma16(qf[1], kf1, sacc[n]);
    }

    // threshold mask + per-row block max
    float sval[4][4];
    float pmax[4] = {-3.0e38f, -3.0e38f, -3.0e38f, -3.0e38f};
#pragma unroll
    for (int n=0;n<4;++n){
      int ki = k0 + n*16 + lr;
#pragma unroll
      for (int r=0;r<4;++r){
        float v = (ki < lim[r]) ? sacc[n][r]*SCALEF : -3.0e38f;
        sval[n][r] = v;
        pmax[r] = fmaxf(pmax[r], v);
      }
    }
#pragma unroll
    for (int r=0;r<4;++r){
      float v = pmax[r];
      v = fmaxf(v, __shfl_xor(v,1,64));
      v = fmaxf(v, __shfl_xor(v,2,64));
      v = fmaxf(v, __shfl_xor(v,4,64));
      v = fmaxf(v, __shfl_xor(v,8,64));
      pmax[r] = v;
    }
    float alpha[4], psum[4];
#pragma unroll
    for (int r=0;r<4;++r){
      float mnew = fmaxf(mrun[r], pmax[r]);
      alpha[r] = __expf(mrun[r] - mnew);
      mrun[r] = mnew;
      psum[r] = 0.f;
    }
#pragma unroll
    for (int r=0;r<4;++r){
      float mn = mrun[r];
#pragma unroll
      for (int n=0;n<4;++n){
        float p = __expf(sval[n][r] - mn);   // masked: -3e38 - mn -> exp -> 0
        psum[r] += p;
        Pl[wid*16 + lg*4 + r][n*16 + lr] = f2b(p);
      }
    }
#pragma unroll
    for (int r=0;r<4;++r){
      float v = psum[r];
      v += __shfl_xor(v,1,64); v += __shfl_xor(v,2,64);
      v += __shfl_xor(v,4,64); v += __shfl_xor(v,8,64);
      lrun[r] = lrun[r]*alpha[r] + v;
    }
#pragma unroll
    for (int n=0;n<4;++n)
#pragma unroll
      for (int r=0;r<4;++r)
        oacc[n][r] *= alpha[r];
    __syncthreads();

    // P @ V
    bf16x8 pf0 = *(const bf16x8*)&Pl[wid*16 + lr][lg*8];
    bf16x8 pf1 = *(const bf16x8*)&Pl[wid*16 + lr][32 + lg*8];
#pragma unroll
    for (int n=0;n<4;++n){
      bf16x8 vf0 = *(const bf16x8*)&Vl[n*16 + lr][lg*8];
      bf16x8 vf1 = *(const bf16x8*)&Vl[n*16 + lr][32 + lg*8];
      oacc[n] = mfma16(pf0, vf0, oacc[n]);
      oacc[n] = mfma16(pf1, vf1, oacc[n]);
    }
    __syncthreads();
  }

#pragma unroll
  for (int n=0;n<4;++n)
#pragma unroll
    for (int r=0;r<4;++r){
      int row = q0 + wid*16 + lg*4 + r;
      int col = hh*64 + n*16 + lr;
      ob[(size_t)row*DIM + col] = f2b(oacc[n][r] / lrun[r]);
    }
}

// ---------------- host ----------------
extern "C" void kernel_launch(void* const* d_in, const int* in_sizes, int n_in,
                              void* d_out, int out_size, void* d_ws, size_t ws_size,
                              hipStream_t stream)
{
  const float* x       = (const float*)d_in[0];
  const float* text    = (const float*)d_in[1];
  const float* w_embed = (const float*)d_in[2];
  const float* b_embed = (const float*)d_in[3];
  const float* w_text  = (const float*)d_in[4];
  const float* b_text  = (const float*)d_in[5];
  const float* ln1_w   = (const float*)d_in[6];
  const float* ln1_b   = (const float*)d_in[7];
  const float* qkv_w   = (const float*)d_in[8];
  const float* qkv_b   = (const float*)d_in[9];
  const float* proj_w  = (const float*)d_in[10];
  const float* proj_b  = (const float*)d_in[11];
  const float* ln2_w   = (const float*)d_in[12];
  const float* ln2_b   = (const float*)d_in[13];
  const float* fc1_w   = (const float*)d_in[14];
  const float* fc1_b   = (const float*)d_in[15];
  const float* fc2_w   = (const float*)d_in[16];
  const float* fc2_b   = (const float*)d_in[17];
  const float* normf_w = (const float*)d_in[18];
  const float* normf_b = (const float*)d_in[19];
  const float* w_out   = (const float*)d_in[20];
  const float* b_out   = (const float*)d_in[21];
  (void)in_sizes; (void)n_in; (void)out_size;

  char* ws = (char*)d_ws;
  size_t off = 0;
  auto alloc = [&](size_t bytes)->void*{
    void* p = ws + off; off += (bytes + 255) & ~(size_t)255; return p;
  };
  u16* wTe  = (u16*)alloc((size_t)1024*768*2);
  u16* wTt  = (u16*)alloc((size_t)1024*4096*2);
  u16* wTq  = (u16*)alloc((size_t)4*3072*1024*2);
  u16* wTp  = (u16*)alloc((size_t)4*1024*1024*2);
  u16* wT1  = (u16*)alloc((size_t)4*4096*1024*2);
  u16* wT2  = (u16*)alloc((size_t)4*1024*4096*2);
  u16* wTo  = (u16*)alloc((size_t)768*1024*2);
  u16* xbf  = (u16*)alloc((size_t)MPAD*768*2);
  u16* tbf  = (u16*)alloc((size_t)128*4096*2);
  float* h  = (float*)alloc((size_t)MPAD*1024*4);
  u16* lno  = (u16*)alloc((size_t)MPAD*1024*2);
  float* qkv= (float*)alloc((size_t)MPAD*3072*4);
  u16* qbuf = (u16*)alloc((size_t)HEADS*MPAD*64*2);
  u16* kbuf = (u16*)alloc((size_t)HEADS*MPAD*64*2);
  u16* vbuf = (u16*)alloc((size_t)HEADS*MPAD*64*2);
  u16* obf  = (u16*)alloc((size_t)MPAD*1024*2);
  u16* mlp  = (u16*)alloc((size_t)MPAD*4096*2);   // also aliases proj split-K partials (2 x MPAD x 1024 fp32)
  float* ct = (float*)alloc((size_t)NTOK*64*4);
  float* st = (float*)alloc((size_t)NTOK*64*4);
  float* partF = (float*)alloc((size_t)4*MPAD*1024*4);  // fc2 / out / text partials
  if (off > ws_size) return;
  float* projPart = (float*)mlp;

  // weights -> transposed bf16
  wtrans_kernel<<<dim3(1024/32, 768/32), 256, 0, stream>>>(w_embed, wTe, 768, 1024);
  wtrans_kernel<<<dim3(1024/32, 4096/32), 256, 0, stream>>>(w_text, wTt, 4096, 1024);
  for (int l=0;l<4;++l){
    wtrans_kernel<<<dim3(3072/32, 1024/32),256,0,stream>>>(qkv_w + (size_t)l*1024*3072, wTq + (size_t)l*3072*1024, 1024, 3072);
    wtrans_kernel<<<dim3(1024/32, 1024/32),256,0,stream>>>(proj_w + (size_t)l*1024*1024, wTp + (size_t)l*1024*1024, 1024, 1024);
    wtrans_kernel<<<dim3(4096/32, 1024/32),256,0,stream>>>(fc1_w + (size_t)l*1024*4096, wT1 + (size_t)l*4096*1024, 1024, 4096);
    wtrans_kernel<<<dim3(1024/32, 4096/32),256,0,stream>>>(fc2_w + (size_t)l*4096*1024, wT2 + (size_t)l*1024*4096, 4096, 1024);
  }
  wtrans_kernel<<<dim3(768/32, 1024/32),256,0,stream>>>(w_out, wTo, 1024, 768);

  f2b_kernel<<<(F_TOK*768+255)/256,256,0,stream>>>(x, xbf, F_TOK*768);
  f2b_kernel<<<(16*4096+255)/256,256,0,stream>>>(text, tbf, 16*4096);
  rope_table_kernel<<<(NTOK*64+255)/256,256,0,stream>>>(ct, st);

  // text embed: M=16, N=1024, K=4096, split-K S=8
  gemm2_kernel<4><<<dim3(8,1,8),256,0,stream>>>(tbf, wTt, nullptr, partF, nullptr,
      16, 1024, 4096, 512, (size_t)16*1024);
  reduce_kernel<<<(16*1024/4+255)/256,256,0,stream>>>(partF, (size_t)16*1024, 8, b_text, nullptr, h, 16*1024, 1024);
  // image embed: M=1568, N=1024, K=768
  gemm2_kernel<0><<<dim3(8,13,1),256,0,stream>>>(xbf, wTe, b_embed, h + (size_t)16*1024, nullptr,
      1568, 1024, 768, 768, 0);

  for (int l=0;l<4;++l){
    ln_kernel<<<MPAD,256,0,stream>>>(h, ln1_w + l*1024, ln1_b + l*1024, lno);
    gemm2_kernel<0><<<dim3(24,13,1),256,0,stream>>>(lno, wTq + (size_t)l*3072*1024, qkv_b + l*3072,
        qkv, nullptr, MPAD, 3072, 1024, 1024, 0);
    rope_apply_kernel<<<(NTOK*512+255)/256,256,0,stream>>>(qkv, ct, st, qbuf, kbuf, vbuf);
    attn_kernel<<<dim3(MPAD/64,16),256,0,stream>>>(qbuf, kbuf, vbuf, obf);
    // proj: split-K S=2, partials alias mlp
    gemm2_kernel<4><<<dim3(8,13,2),256,0,stream>>>(obf, wTp + (size_t)l*1024*1024, nullptr,
        projPart, nullptr, MPAD, 1024, 1024, 512, (size_t)MPAD*1024);
    reduce_kernel<<<(MPAD*1024/4+255)/256,256,0,stream>>>(projPart, (size_t)MPAD*1024, 2,
        proj_b + l*1024, h, h, MPAD*1024, 1024);
    ln_kernel<<<MPAD,256,0,stream>>>(h, ln2_w + l*1024, ln2_b + l*1024, lno);
    gemm2_kernel<3><<<dim3(32,13,1),256,0,stream>>>(lno, wT1 + (size_t)l*4096*1024, fc1_b + l*4096,
        nullptr, mlp, MPAD, 4096, 1024, 1024, 0);
    // fc2: split-K S=4
    gemm2_kernel<4><<<dim3(8,13,4),256,0,stream>>>(mlp, wT2 + (size_t)l*1024*4096, nullptr,
        partF, nullptr, MPAD, 1024, 4096, 1024, (size_t)MPAD*1024);
    reduce_kernel<<<(MPAD*1024/4+255)/256,256,0,stream>>>(partF, (size_t)MPAD*1024, 4,
        fc2_b + l*1024, h, h, MPAD*1024, 1024);
  }

  ln_kernel<<<F_TOK,256,0,stream>>>(h + (size_t)16*1024, normf_w, normf_b, lno);
  // out: M=1568, N=768, K=1024, split-K S=4
  gemm2_kernel<4><<<dim3(6,13,4),256,0,stream>>>(lno, wTo, nullptr, partF, nullptr,
      F_TOK, 768, 1024, 256, (size_t)F_TOK*768);
  reduce_kernel<<<(F_TOK*768/4+255)/256,256,0,stream>>>(partF, (size_t)F_TOK*768, 4,
      b_out, nullptr, (float*)d_out, F_TOK*768, 768);
}

// Round 6
// 985.385 us; speedup vs baseline: 1.7217x; 1.0825x over previous
//
#include <hip/hip_runtime.h>
#include <hip/hip_bf16.h>
#include <math.h>

#define HEADS 16
#define DIM 1024
#define N_TEXT 16
#define F_TOK 1568
#define NTOK 1584
#define MPAD 1664
#define SCALEF 0.125f
#define NSPLIT 4

typedef unsigned int uint;
typedef unsigned short u16;

typedef __bf16 bf16x8 __attribute__((ext_vector_type(8)));
typedef float f32x4 __attribute__((ext_vector_type(4)));

__device__ inline u16 f2b(float f){
  uint u = __builtin_bit_cast(uint, f);
  uint r = u + 0x7fffu + ((u >> 16) & 1u);
  return (u16)(r >> 16);
}

__device__ inline f32x4 mfma16(bf16x8 a, bf16x8 b, f32x4 c){
  return __builtin_amdgcn_mfma_f32_16x16x32_bf16(a, b, c, 0, 0, 0);
}

__device__ __forceinline__ void gload16(const u16* g, u16* l){
  __builtin_amdgcn_global_load_lds(
      (__attribute__((address_space(1))) u16*)const_cast<u16*>(g),
      (__attribute__((address_space(3))) u16*)l, 16, 0, 0);
}

// ---------------- weight transpose fp32[K][N] -> bf16[N][K] ----------------
__global__ __launch_bounds__(256) void wtrans_kernel(const float* __restrict__ src,
                                                     u16* __restrict__ dst, int K, int N){
  __shared__ float tile[32][33];
  int n0 = blockIdx.x * 32, k0 = blockIdx.y * 32;
  int t = threadIdx.x;
  int col = t & 31, rb = t >> 5;
#pragma unroll
  for (int p = 0; p < 4; ++p){
    int row = p*8 + rb;
    tile[row][col] = src[(size_t)(k0+row)*N + n0 + col];
  }
  __syncthreads();
#pragma unroll
  for (int p = 0; p < 4; ++p){
    int rn = p*8 + rb;
    dst[(size_t)(n0+rn)*K + k0 + col] = f2b(tile[col][rn]);
  }
}

// ---------------- flat fp32 -> bf16 ----------------
__global__ __launch_bounds__(256) void f2b_kernel(const float* __restrict__ src,
                                                  u16* __restrict__ dst, int n){
  int i = blockIdx.x*256 + threadIdx.x;
  if (i < n) dst[i] = f2b(src[i]);
}

// ---------------- rope tables ----------------
__global__ __launch_bounds__(256) void rope_table_kernel(float* __restrict__ ct,
                                                         float* __restrict__ st){
  int i = blockIdx.x*256 + threadIdx.x;
  if (i >= NTOK*64) return;
  int n = i >> 6, d = i & 63;
  float f = 0.f;
  if (n >= N_TEXT){
    int id = n - N_TEXT;
    int p0 = id / 196;
    int p1 = (id % 196) / 14;
    int p2 = id % 14;
    float pos = 0.f; int j = -1;
    if (d < 20){ pos = (float)p0; j = d >> 1; }
    else if (d < 40){ pos = (float)p1; j = (d-20) >> 1; }
    else if (d < 60){ pos = (float)p2; j = (d-40) >> 1; }
    if (j >= 0){
      float inv = powf(10000.f, -(float)j * 0.1f);
      f = pos * inv;
    }
  }
  ct[i] = cosf(f);
  st[i] = sinf(f);
}

// ---------------- rope apply + split qkv -> per-head bf16 ----------------
__global__ __launch_bounds__(256) void rope_apply_kernel(const float* __restrict__ qkv,
    const float* __restrict__ ct, const float* __restrict__ st,
    u16* __restrict__ qb, u16* __restrict__ kb, u16* __restrict__ vb){
  int i = blockIdx.x*256 + threadIdx.x;       // NTOK*16*32
  if (i >= NTOK*HEADS*32) return;
  int n = i / 512;
  int rem = i & 511;
  int h = rem >> 5;
  int d0 = (rem & 31) * 2;
  size_t base = (size_t)n*3072 + h*64 + d0;
  float q0 = qkv[base],      q1 = qkv[base+1];
  float k0 = qkv[base+1024], k1 = qkv[base+1025];
  float v0 = qkv[base+2048], v1 = qkv[base+2049];
  float c = ct[n*64+d0], s = st[n*64+d0];
  size_t ob = ((size_t)h*MPAD + n)*64 + d0;
  qb[ob]   = f2b(q0*c - q1*s);
  qb[ob+1] = f2b(q1*c + q0*s);
  kb[ob]   = f2b(k0*c - k1*s);
  kb[ob+1] = f2b(k1*c + k0*s);
  vb[ob]   = f2b(v0);
  vb[ob+1] = f2b(v1);
}

// ---------------- layernorm (fp32 in, bf16 out) ----------------
__global__ __launch_bounds__(256) void ln_kernel(const float* __restrict__ x,
    const float* __restrict__ w, const float* __restrict__ b, u16* __restrict__ out){
  int row = blockIdx.x, t = threadIdx.x;
  const float* xr = x + (size_t)row * DIM;
  float4 v = *(const float4*)&xr[t*4];
  float s = v.x+v.y+v.z+v.w;
  float ss = v.x*v.x+v.y*v.y+v.z*v.z+v.w*v.w;
#pragma unroll
  for (int o=32;o>0;o>>=1){ s += __shfl_down(s,o,64); ss += __shfl_down(ss,o,64); }
  __shared__ float red[8];
  int wid = t>>6;
  if ((t&63)==0){ red[wid] = s; red[4+wid] = ss; }
  __syncthreads();
  float S = red[0]+red[1]+red[2]+red[3];
  float SS = red[4]+red[5]+red[6]+red[7];
  float mean = S * (1.0f/1024.0f);
  float var = SS * (1.0f/1024.0f) - mean*mean;
  float inv = rsqrtf(var + 1e-5f);
  ushort4 o4;
  o4.x = f2b((v.x-mean)*inv*w[t*4+0]+b[t*4+0]);
  o4.y = f2b((v.y-mean)*inv*w[t*4+1]+b[t*4+1]);
  o4.z = f2b((v.z-mean)*inv*w[t*4+2]+b[t*4+2]);
  o4.w = f2b((v.w-mean)*inv*w[t*4+3]+b[t*4+3]);
  *(ushort4*)&out[(size_t)row*DIM + t*4] = o4;
}

// ================= pipelined bf16 MFMA GEMM =================
// C = A[M][K] @ BT[N][K]^T ; 128x128 tile, BK=64, double-buffered LDS via
// global_load_lds (linear dest) + XOR-swizzled source/read (slot ^= row&7).
// EPI: 0 = +bias -> fp32 ; 3 = +bias,gelu -> bf16 ; 4 = raw partial fp32 (split-K)
template<int EPI>
__global__ __launch_bounds__(256, 2)
void gemm2_kernel(const u16* __restrict__ A, const u16* __restrict__ BT,
                  const float* __restrict__ bias,
                  float* __restrict__ outF, u16* __restrict__ outB,
                  int M, int N, int K, int klen, size_t partStride)
{
  __shared__ u16 L[2][2][128*64];   // [buf][A/B][row*64 + swizzled slot]
  const int t = threadIdx.x, wid = t >> 6, lane = t & 63;
  const int lr = lane & 15, lg = lane >> 4;
  const int wr = wid >> 1, wc = wid & 1;
  const int m0 = blockIdx.y * 128, n0 = blockIdx.x * 128;
  const int kstart = blockIdx.z * klen;

  // staging: chunk c = wid*4+j covers rows c*8..c*8+7; lane covers (row, slot)
  const int srow = lane >> 3;
  const int scol = ((lane & 7) ^ srow) * 8;          // inverse-swizzled source column
  const u16* Ast = A  + (size_t)(m0 + srow)*K + kstart + scol;
  const u16* Bst = BT + (size_t)(n0 + srow)*K + kstart + scol;

  // swizzled read slots (involution: same XOR as source)
  const int s0 = (lg     ) ^ (lr & 7);
  const int s1 = (lg + 4 ) ^ (lr & 7);
  const int aBase = (wr*64 + lr)*64;
  const int bBase = (wc*64 + lr)*64;

  f32x4 acc[4][4] = {};
  const int nk = klen >> 6;

  auto STAGE = [&](int buf, int step){
    const u16* a = Ast + (size_t)step*64;
    const u16* b = Bst + (size_t)step*64;
#pragma unroll
    for (int j = 0; j < 4; ++j){
      int c = wid*4 + j;
      gload16(a + (size_t)c*8*K, &L[buf][0][c*512]);
      gload16(b + (size_t)c*8*K, &L[buf][1][c*512]);
    }
  };

  STAGE(0, 0);
  __syncthreads();
  int cur = 0;
  for (int tt = 0; tt < nk; ++tt){
    if (tt + 1 < nk) STAGE(cur ^ 1, tt + 1);
    const u16* Ab = &L[cur][0][0];
    const u16* Bb = &L[cur][1][0];
    bf16x8 af[2][4], bv[2][4];
#pragma unroll
    for (int m = 0; m < 4; ++m){
      af[0][m] = *(const bf16x8*)&Ab[aBase + m*1024 + s0*8];
      af[1][m] = *(const bf16x8*)&Ab[aBase + m*1024 + s1*8];
    }
#pragma unroll
    for (int n = 0; n < 4; ++n){
      bv[0][n] = *(const bf16x8*)&Bb[bBase + n*1024 + s0*8];
      bv[1][n] = *(const bf16x8*)&Bb[bBase + n*1024 + s1*8];
    }
#pragma unroll
    for (int ks = 0; ks < 2; ++ks)
#pragma unroll
      for (int m = 0; m < 4; ++m)
#pragma unroll
        for (int n = 0; n < 4; ++n)
          acc[m][n] = mfma16(af[ks][m], bv[ks][n], acc[m][n]);
    __syncthreads();
    cur ^= 1;
  }

#pragma unroll
  for (int m = 0; m < 4; ++m){
#pragma unroll
    for (int r = 0; r < 4; ++r){
      int row = m0 + wr*64 + m*16 + lg*4 + r;
      if (row >= M) continue;
#pragma unroll
      for (int n = 0; n < 4; ++n){
        int col = n0 + wc*64 + n*16 + lr;
        float v = acc[m][n][r];
        if constexpr (EPI == 4){
          outF[partStride*blockIdx.z + (size_t)row*N + col] = v;
        } else if constexpr (EPI == 3){
          v += bias[col];
          v = 0.5f * v * (1.0f + erff(v * 0.70710678118654752f));
          outB[(size_t)row*N + col] = f2b(v);
        } else {
          v += bias[col];
          outF[(size_t)row*N + col] = v;
        }
      }
    }
  }
}

// ---------------- split-K reduce: out = bias + (resid?) + sum_s part[s] ----------------
__global__ __launch_bounds__(256) void reduce_kernel(const float* __restrict__ part,
    size_t stride, int S, const float* __restrict__ bias, const float* __restrict__ resid,
    float* __restrict__ out, int MN, int N){
  int i = (blockIdx.x*256 + threadIdx.x)*4;
  if (i >= MN) return;
  float4 v = *(const float4*)&bias[i % N];
  if (resid){
    float4 r = *(const float4*)&resid[i];
    v.x += r.x; v.y += r.y; v.z += r.z; v.w += r.w;
  }
  for (int s = 0; s < S; ++s){
    float4 p = *(const float4*)&part[(size_t)s*stride + i];
    v.x += p.x; v.y += p.y; v.z += p.z; v.w += p.w;
  }
  *(float4*)&out[i] = v;
}

// ---------------- split-KV flash attention (partials) ----------------
// Mask: allowed(qi,ki) <=> ki < limit(qi); limit monotone => per-block k-tile
// count nkt; z-block processes tiles [z*tpz, min(nkt,(z+1)*tpz)).
// Partials: attO fp32 [z][head][row][64], attM/attL [z][head][row].
__global__ __launch_bounds__(256)
void attn_split_kernel(const u16* __restrict__ qb, const u16* __restrict__ kb,
                       const u16* __restrict__ vb, float* __restrict__ attO,
                       float* __restrict__ attM, float* __restrict__ attL)
{
  __shared__ u16 Kl[64][72];
  __shared__ u16 Vl[64][72];    // V^T: [d][kk]
  __shared__ u16 Pl[64][72];
  const int hh = blockIdx.y;
  const int q0 = blockIdx.x * 64;
  const int zz = blockIdx.z;
  const int t = threadIdx.x, wid = t>>6, lane = t&63, lr = lane&15, lg = lane>>4;
  const size_t hbase = (size_t)hh*MPAD*64;
  const size_t pbase = (size_t)(zz*HEADS + hh)*MPAD;

  bf16x8 qf[2];
  {
    int row = q0 + wid*16 + lr;
    qf[0] = *(const bf16x8*)&qb[hbase + (size_t)row*64 + lg*8];
    qf[1] = *(const bf16x8*)&qb[hbase + (size_t)row*64 + 32 + lg*8];
  }

  int lim[4];
#pragma unroll
  for (int r=0;r<4;++r){
    int qi = q0 + wid*16 + lg*4 + r;
    int L = (qi < N_TEXT) ? (qi + 1) : (16 + ((qi - 16)/196 + 1)*196);
    lim[r] = min(L, NTOK);
  }
  const int qlast = min(q0 + 63, NTOK - 1);
  const int kend  = (qlast < N_TEXT) ? (qlast + 1)
                                     : min(16 + ((qlast - 16)/196 + 1)*196, NTOK);
  const int nkt = (kend + 63) >> 6;
  const int tpz = (nkt + NSPLIT - 1) / NSPLIT;
  const int kb0 = zz * tpz;
  const int kb1 = min(nkt, kb0 + tpz);

  float mrun[4], lrun[4];
#pragma unroll
  for (int i=0;i<4;++i){ mrun[i] = -3.0e38f; lrun[i] = 0.0f; }
  f32x4 oacc[4] = {};

  for (int kbi = kb0; kbi < kb1; ++kbi){
    const int k0 = kbi*64;
#pragma unroll
    for (int p=0;p<2;++p){                  // stage K: 64 rows x 64 d
      int sidx = t + p*256;
      int row = sidx >> 3, c8 = (sidx & 7) * 8;
      *(uint4*)&Kl[row][c8] = *(const uint4*)&kb[hbase + (size_t)(k0 + row)*64 + c8];
    }
#pragma unroll
    for (int p=0;p<2;++p){                  // stage V^T
      int sidx = t + p*256;
      int kk = sidx & 63, d8 = (sidx >> 6) * 8;
      union { uint4 u; u16 s[8]; } tv;
      tv.u = *(const uint4*)&vb[hbase + (size_t)(k0 + kk)*64 + d8];
#pragma unroll
      for (int j=0;j<8;++j) Vl[d8+j][kk] = tv.s[j];
    }
    __syncthreads();

    // QK^T: 16 q-rows x 64 keys per wave
    f32x4 sacc[4] = {};
#pragma unroll
    for (int n=0;n<4;++n){
      bf16x8 kf0 = *(const bf16x8*)&Kl[n*16 + lr][lg*8];
      bf16x8 kf1 = *(const bf16x8*)&Kl[n*16 + lr][32 + lg*8];
      sacc[n] = mfma16(qf[0], kf0, sacc[n]);
      sacc[n] = mfma16(qf[1], kf1, sacc[n]);
    }

    // threshold mask + per-row block max
    float sval[4][4];
    float pmax[4] = {-3.0e38f, -3.0e38f, -3.0e38f, -3.0e38f};
#pragma unroll
    for (int n=0;n<4;++n){
      int ki = k0 + n*16 + lr;
#pragma unroll
      for (int r=0;r<4;++r){
        float v = (ki < lim[r]) ? sacc[n][r]*SCALEF : -3.0e38f;
        sval[n][r] = v;
        pmax[r] = fmaxf(pmax[r], v);
      }
    }
#pragma unroll
    for (int r=0;r<4;++r){
      float v = pmax[r];
      v = fmaxf(v, __shfl_xor(v,1,64));
      v = fmaxf(v, __shfl_xor(v,2,64));
      v = fmaxf(v, __shfl_xor(v,4,64));
      v = fmaxf(v, __shfl_xor(v,8,64));
      pmax[r] = v;
    }
    float alpha[4], psum[4];
#pragma unroll
    for (int r=0;r<4;++r){
      float mnew = fmaxf(mrun[r], pmax[r]);
      alpha[r] = __expf(mrun[r] - mnew);
      mrun[r] = mnew;
      psum[r] = 0.f;
    }
#pragma unroll
    for (int r=0;r<4;++r){
      float mn = mrun[r];
#pragma unroll
      for (int n=0;n<4;++n){
        float p = __expf(sval[n][r] - mn);   // masked: exp(-huge) -> 0
        psum[r] += p;
        Pl[wid*16 + lg*4 + r][n*16 + lr] = f2b(p);
      }
    }
#pragma unroll
    for (int r=0;r<4;++r){
      float v = psum[r];
      v += __shfl_xor(v,1,64); v += __shfl_xor(v,2,64);
      v += __shfl_xor(v,4,64); v += __shfl_xor(v,8,64);
      lrun[r] = lrun[r]*alpha[r] + v;
    }
#pragma unroll
    for (int n=0;n<4;++n)
#pragma unroll
      for (int r=0;r<4;++r)
        oacc[n][r] *= alpha[r];
    __syncthreads();

    // P @ V
    bf16x8 pf0 = *(const bf16x8*)&Pl[wid*16 + lr][lg*8];
    bf16x8 pf1 = *(const bf16x8*)&Pl[wid*16 + lr][32 + lg*8];
#pragma unroll
    for (int n=0;n<4;++n){
      bf16x8 vf0 = *(const bf16x8*)&Vl[n*16 + lr][lg*8];
      bf16x8 vf1 = *(const bf16x8*)&Vl[n*16 + lr][32 + lg*8];
      oacc[n] = mfma16(pf0, vf0, oacc[n]);
      oacc[n] = mfma16(pf1, vf1, oacc[n]);
    }
    __syncthreads();
  }

  // write partials
#pragma unroll
  for (int n=0;n<4;++n)
#pragma unroll
    for (int r=0;r<4;++r){
      int row = q0 + wid*16 + lg*4 + r;
      attO[(pbase + row)*64 + n*16 + lr] = oacc[n][r];
    }
  if (lr == 0){
#pragma unroll
    for (int r=0;r<4;++r){
      int row = q0 + wid*16 + lg*4 + r;
      attM[pbase + row] = mrun[r];
      attL[pbase + row] = lrun[r];
    }
  }
}

// ---------------- combine split-KV partials -> bf16 ob ----------------
__global__ __launch_bounds__(256)
void attn_combine_kernel(const float* __restrict__ attO, const float* __restrict__ attM,
                         const float* __restrict__ attL, u16* __restrict__ ob)
{
  int i = blockIdx.x*256 + threadIdx.x;     // (row*16 + head)*16 + dchunk
  if (i >= MPAD*HEADS*16) return;
  int dchunk = i & 15;
  int head = (i >> 4) & 15;
  int row = i >> 8;
  float m = -3.0e38f;
#pragma unroll
  for (int z=0; z<NSPLIT; ++z)
    m = fmaxf(m, attM[(size_t)(z*HEADS+head)*MPAD + row]);
  float l = 0.f;
  float4 o = {0.f,0.f,0.f,0.f};
#pragma unroll
  for (int z=0; z<NSPLIT; ++z){
    size_t pb = (size_t)(z*HEADS+head)*MPAD + row;
    float w = __expf(attM[pb] - m);
    l += w * attL[pb];
    float4 p = *(const float4*)&attO[pb*64 + dchunk*4];
    o.x += w*p.x; o.y += w*p.y; o.z += w*p.z; o.w += w*p.w;
  }
  float inv = 1.0f / fmaxf(l, 1e-30f);
  ushort4 o4;
  o4.x = f2b(o.x*inv); o4.y = f2b(o.y*inv);
  o4.z = f2b(o.z*inv); o4.w = f2b(o.w*inv);
  *(ushort4*)&ob[(size_t)row*DIM + head*64 + dchunk*4] = o4;
}

// ---------------- host ----------------
extern "C" void kernel_launch(void* const* d_in, const int* in_sizes, int n_in,
                              void* d_out, int out_size, void* d_ws, size_t ws_size,
                              hipStream_t stream)
{
  const float* x       = (const float*)d_in[0];
  const float* text    = (const float*)d_in[1];
  const float* w_embed = (const float*)d_in[2];
  const float* b_embed = (const float*)d_in[3];
  const float* w_text  = (const float*)d_in[4];
  const float* b_text  = (const float*)d_in[5];
  const float* ln1_w   = (const float*)d_in[6];
  const float* ln1_b   = (const float*)d_in[7];
  const float* qkv_w   = (const float*)d_in[8];
  const float* qkv_b   = (const float*)d_in[9];
  const float* proj_w  = (const float*)d_in[10];
  const float* proj_b  = (const float*)d_in[11];
  const float* ln2_w   = (const float*)d_in[12];
  const float* ln2_b   = (const float*)d_in[13];
  const float* fc1_w   = (const float*)d_in[14];
  const float* fc1_b   = (const float*)d_in[15];
  const float* fc2_w   = (const float*)d_in[16];
  const float* fc2_b   = (const float*)d_in[17];
  const float* normf_w = (const float*)d_in[18];
  const float* normf_b = (const float*)d_in[19];
  const float* w_out   = (const float*)d_in[20];
  const float* b_out   = (const float*)d_in[21];
  (void)in_sizes; (void)n_in; (void)out_size;

  char* ws = (char*)d_ws;
  size_t off = 0;
  auto alloc = [&](size_t bytes)->void*{
    void* p = ws + off; off += (bytes + 255) & ~(size_t)255; return p;
  };
  u16* wTe  = (u16*)alloc((size_t)1024*768*2);
  u16* wTt  = (u16*)alloc((size_t)1024*4096*2);
  u16* wTq  = (u16*)alloc((size_t)4*3072*1024*2);
  u16* wTp  = (u16*)alloc((size_t)4*1024*1024*2);
  u16* wT1  = (u16*)alloc((size_t)4*4096*1024*2);
  u16* wT2  = (u16*)alloc((size_t)4*1024*4096*2);
  u16* wTo  = (u16*)alloc((size_t)768*1024*2);
  u16* xbf  = (u16*)alloc((size_t)MPAD*768*2);
  u16* tbf  = (u16*)alloc((size_t)128*4096*2);
  float* h  = (float*)alloc((size_t)MPAD*1024*4);
  u16* lno  = (u16*)alloc((size_t)MPAD*1024*2);
  float* qkv= (float*)alloc((size_t)MPAD*3072*4);
  u16* qbuf = (u16*)alloc((size_t)HEADS*MPAD*64*2);
  u16* kbuf = (u16*)alloc((size_t)HEADS*MPAD*64*2);
  u16* vbuf = (u16*)alloc((size_t)HEADS*MPAD*64*2);
  u16* obf  = (u16*)alloc((size_t)MPAD*1024*2);
  u16* mlp  = (u16*)alloc((size_t)MPAD*4096*2);   // also aliases proj split-K partials (2 x MPAD x 1024 fp32)
  float* ct = (float*)alloc((size_t)NTOK*64*4);
  float* st = (float*)alloc((size_t)NTOK*64*4);
  float* partF = (float*)alloc((size_t)4*MPAD*1024*4);  // fc2/out/text partials; aliases attn O-partials
  float* attM = (float*)alloc((size_t)NSPLIT*HEADS*MPAD*4);
  float* attL = (float*)alloc((size_t)NSPLIT*HEADS*MPAD*4);
  if (off > ws_size) return;
  float* projPart = (float*)mlp;

  // weights -> transposed bf16
  wtrans_kernel<<<dim3(1024/32, 768/32), 256, 0, stream>>>(w_embed, wTe, 768, 1024);
  wtrans_kernel<<<dim3(1024/32, 4096/32), 256, 0, stream>>>(w_text, wTt, 4096, 1024);
  for (int l=0;l<4;++l){
    wtrans_kernel<<<dim3(3072/32, 1024/32),256,0,stream>>>(qkv_w + (size_t)l*1024*3072, wTq + (size_t)l*3072*1024, 1024, 3072);
    wtrans_kernel<<<dim3(1024/32, 1024/32),256,0,stream>>>(proj_w + (size_t)l*1024*1024, wTp + (size_t)l*1024*1024, 1024, 1024);
    wtrans_kernel<<<dim3(4096/32, 1024/32),256,0,stream>>>(fc1_w + (size_t)l*1024*4096, wT1 + (size_t)l*4096*1024, 1024, 4096);
    wtrans_kernel<<<dim3(1024/32, 4096/32),256,0,stream>>>(fc2_w + (size_t)l*4096*1024, wT2 + (size_t)l*1024*4096, 4096, 1024);
  }
  wtrans_kernel<<<dim3(768/32, 1024/32),256,0,stream>>>(w_out, wTo, 1024, 768);

  f2b_kernel<<<(F_TOK*768+255)/256,256,0,stream>>>(x, xbf, F_TOK*768);
  f2b_kernel<<<(16*4096+255)/256,256,0,stream>>>(text, tbf, 16*4096);
  rope_table_kernel<<<(NTOK*64+255)/256,256,0,stream>>>(ct, st);

  // text embed: M=16, N=1024, K=4096, split-K S=8
  gemm2_kernel<4><<<dim3(8,1,8),256,0,stream>>>(tbf, wTt, nullptr, partF, nullptr,
      16, 1024, 4096, 512, (size_t)16*1024);
  reduce_kernel<<<(16*1024/4+255)/256,256,0,stream>>>(partF, (size_t)16*1024, 8, b_text, nullptr, h, 16*1024, 1024);
  // image embed: M=1568, N=1024, K=768
  gemm2_kernel<0><<<dim3(8,13,1),256,0,stream>>>(xbf, wTe, b_embed, h + (size_t)16*1024, nullptr,
      1568, 1024, 768, 768, 0);

  for (int l=0;l<4;++l){
    ln_kernel<<<MPAD,256,0,stream>>>(h, ln1_w + l*1024, ln1_b + l*1024, lno);
    gemm2_kernel<0><<<dim3(24,13,1),256,0,stream>>>(lno, wTq + (size_t)l*3072*1024, qkv_b + l*3072,
        qkv, nullptr, MPAD, 3072, 1024, 1024, 0);
    rope_apply_kernel<<<(NTOK*512+255)/256,256,0,stream>>>(qkv, ct, st, qbuf, kbuf, vbuf);
    attn_split_kernel<<<dim3(MPAD/64,HEADS,NSPLIT),256,0,stream>>>(qbuf, kbuf, vbuf,
        partF, attM, attL);
    attn_combine_kernel<<<(MPAD*HEADS*16+255)/256,256,0,stream>>>(partF, attM, attL, obf);
    // proj: split-K S=2, partials alias mlp
    gemm2_kernel<4><<<dim3(8,13,2),256,0,stream>>>(obf, wTp + (size_t)l*1024*1024, nullptr,
        projPart, nullptr, MPAD, 1024, 1024, 512, (size_t)MPAD*1024);
    reduce_kernel<<<(MPAD*1024/4+255)/256,256,0,stream>>>(projPart, (size_t)MPAD*1024, 2,
        proj_b + l*1024, h, h, MPAD*1024, 1024);
    ln_kernel<<<MPAD,256,0,stream>>>(h, ln2_w + l*1024, ln2_b + l*1024, lno);
    gemm2_kernel<3><<<dim3(32,13,1),256,0,stream>>>(lno, wT1 + (size_t)l*4096*1024, fc1_b + l*4096,
        nullptr, mlp, MPAD, 4096, 1024, 1024, 0);
    // fc2: split-K S=4
    gemm2_kernel<4><<<dim3(8,13,4),256,0,stream>>>(mlp, wT2 + (size_t)l*1024*4096, nullptr,
        partF, nullptr, MPAD, 1024, 4096, 1024, (size_t)MPAD*1024);
    reduce_kernel<<<(MPAD*1024/4+255)/256,256,0,stream>>>(partF, (size_t)MPAD*1024, 4,
        fc2_b + l*1024, h, h, MPAD*1024, 1024);
  }

  ln_kernel<<<F_TOK,256,0,stream>>>(h + (size_t)16*1024, normf_w, normf_b, lno);
  // out: M=1568, N=768, K=1024, split-K S=4
  gemm2_kernel<4><<<dim3(6,13,4),256,0,stream>>>(lno, wTo, nullptr, partF, nullptr,
      F_TOK, 768, 1024, 256, (size_t)F_TOK*768);
  reduce_kernel<<<(F_TOK*768/4+255)/256,256,0,stream>>>(partF, (size_t)F_TOK*768, 4,
      b_out, nullptr, (float*)d_out, F_TOK*768, 768);
}